// Round 2
// baseline (20004.454 us; speedup 1.0000x reference)
//
#include <hip/hip_runtime.h>
#include <hip/hip_bf16.h>
#include <math.h>

typedef __hip_bfloat16 bf16;

constexpr int B_ = 8, S_ = 1024, F_ = 8, D_ = 512, H_ = 8, E_ = 4;
constexpr int T_  = B_ * S_;       // 8192 tokens
constexpr int D3_ = 3 * D_;        // 1536

__device__ __forceinline__ float b2f(bf16 v) { return __bfloat162float(v); }
// flag-dispatched input load: bf=1 -> bf16, bf=0 -> fp32 (wave-uniform branch)
__device__ __forceinline__ float ldin(const void* p, size_t i, int bf) {
  return bf ? __bfloat162float(((const bf16*)p)[i]) : ((const float*)p)[i];
}

// ---------------- dtype detector: writes flag[0]=1 if inputs are bf16 ----------------
// x ~ N(0,1). As bf16, even uint16 elements have exponent bits in a sane range ~always.
// As fp32, even uint16s are low mantissa halves -> ~19% in range. Threshold 64/128.
__global__ void detect_kernel(const void* __restrict__ x, int* __restrict__ flag) {
  if (threadIdx.x == 0 && blockIdx.x == 0) {
    const unsigned short* u = (const unsigned short*)x;
    int c = 0;
    for (int i = 0; i < 256; i += 2) {
      int ex = (u[i] >> 7) & 0xFF;
      if (ex >= 96 && ex <= 144) c++;
    }
    flag[0] = (c >= 64) ? 1 : 0;
  }
}

// ---------------- instance norm over time axis (ddof=1, eps on std) ----------------
__global__ __launch_bounds__(256) void instnorm_kernel(const void* __restrict__ x,
                                                       float* __restrict__ xn,
                                                       const int* __restrict__ flag) {
  const int bf = flag[0];
  int b = blockIdx.x / F_, f = blockIdx.x % F_;
  int tid = threadIdx.x;
  __shared__ float red[256];
  const int base = b * S_ * F_ + f;
  float s = 0.f;
  for (int j = tid; j < S_; j += 256) s += ldin(x, base + j * F_, bf);
  red[tid] = s; __syncthreads();
  for (int w = 128; w; w >>= 1) { if (tid < w) red[tid] += red[tid + w]; __syncthreads(); }
  float mean = red[0] / S_;
  __syncthreads();
  float v = 0.f;
  for (int j = tid; j < S_; j += 256) { float d = ldin(x, base + j * F_, bf) - mean; v += d * d; }
  red[tid] = v; __syncthreads();
  for (int w = 128; w; w >>= 1) { if (tid < w) red[tid] += red[tid + w]; __syncthreads(); }
  float inv = 1.f / (sqrtf(red[0] / (float)(S_ - 1)) + 1e-5f);
  for (int j = tid; j < S_; j += 256) xn[base + j * F_] = (ldin(x, base + j * F_, bf) - mean) * inv;
}

// ---------------- input projection + freq emb + positional encoding ----------------
__global__ __launch_bounds__(256) void input_proj_kernel(const float* __restrict__ xn,
                                                         const void* __restrict__ Wp,
                                                         const void* __restrict__ bp,
                                                         const void* __restrict__ femb,
                                                         const int* __restrict__ freq_idx,
                                                         float* __restrict__ h,
                                                         const int* __restrict__ flag) {
  const int bf = flag[0];
  int idx = blockIdx.x * 256 + threadIdx.x;   // < T_*D_
  int d = idx % D_;
  int t = idx / D_;
  int s = t % S_;
  int fi = freq_idx[0];
  float acc = ldin(bp, d, bf) + ldin(femb, (size_t)fi * D_ + d, bf);
  int i2 = d & ~1;
  const float cexp = -9.2103403719761836f / (float)D_;   // -ln(10000)/D
  float ang = (float)s * expf((float)i2 * cexp);
  acc += (d & 1) ? cosf(ang) : sinf(ang);
  const float* xr = xn + t * F_;
#pragma unroll
  for (int f = 0; f < F_; f++) acc += xr[f] * ldin(Wp, (size_t)d * F_ + f, bf);
  h[idx] = acc;
}

// ---------------- generic tiled GEMM: C[m,n] = sum_k A[m,k] * W[n,k] (+epilogue) -----
// MODE 0: A fp32, C fp32, +bias
// MODE 1: A fp32, C bf16, c = cw[m*4+eidx] * relu(acc + bias[n])  (MoE mat1, expert eidx)
// MODE 2: A bf16 (hid_e), C fp32;
//         eidx==0: C = acc + sum_e cw[m*4+e]*eb2[e*D+n]; else C += acc (MoE mat2)
template <int MODE>
__global__ __launch_bounds__(256) void gemm_kernel(
    const void* __restrict__ A_, const void* __restrict__ Wt, size_t woff,
    const void* __restrict__ bias, size_t boff, void* __restrict__ C_,
    int N, int Kd, int lda, int ldc,
    const float* __restrict__ cw, const void* __restrict__ eb2p, size_t e2off,
    int eidx, const int* __restrict__ flag) {
  const int wbf = flag[0];
  constexpr int BK = 16;
  __shared__ __align__(16) float As[BK][68];
  __shared__ __align__(16) float Ws[BK][68];
  int tid = threadIdx.x;
  int tx = tid & 15, ty = tid >> 4;
  int n0 = blockIdx.x * 64;
  int m0 = blockIdx.y * 64;
  int lk = tid & 15;         // k within tile
  int lm = tid >> 4;         // row group
  float acc[4][4] = {};
  for (int k0 = 0; k0 < Kd; k0 += BK) {
    int k = k0 + lk;
#pragma unroll
    for (int p = 0; p < 4; p++) {
      int mm = lm + p * 16;
      float av = (MODE == 2) ? b2f(((const bf16*)A_)[(size_t)(m0 + mm) * lda + k])
                             : ((const float*)A_)[(size_t)(m0 + mm) * lda + k];
      As[lk][mm] = av;
      int nn = lm + p * 16;
      Ws[lk][nn] = ldin(Wt, woff + (size_t)(n0 + nn) * Kd + k, wbf);
    }
    __syncthreads();
#pragma unroll
    for (int kk = 0; kk < BK; kk++) {
      float4 a4 = *(const float4*)&As[kk][ty * 4];
      float4 b4 = *(const float4*)&Ws[kk][tx * 4];
      float aa[4] = {a4.x, a4.y, a4.z, a4.w};
      float bb[4] = {b4.x, b4.y, b4.z, b4.w};
#pragma unroll
      for (int i = 0; i < 4; i++)
#pragma unroll
        for (int j = 0; j < 4; j++) acc[i][j] += aa[i] * bb[j];
    }
    __syncthreads();
  }
#pragma unroll
  for (int i = 0; i < 4; i++) {
    int m = m0 + ty * 4 + i;
#pragma unroll
    for (int j = 0; j < 4; j++) {
      int n = n0 + tx * 4 + j;
      float v = acc[i][j];
      if (MODE == 0) {
        ((float*)C_)[(size_t)m * ldc + n] = v + ldin(bias, boff + n, wbf);
      } else if (MODE == 1) {
        v += ldin(bias, boff + n, wbf);
        ((bf16*)C_)[(size_t)m * ldc + n] =
            __float2bfloat16(fmaxf(v, 0.f) * cw[m * 4 + eidx]);
      } else {
        float* cp = (float*)C_ + (size_t)m * ldc + n;
        if (eidx == 0) {
          float badd = 0.f;
#pragma unroll
          for (int e2 = 0; e2 < 4; e2++)
            badd += cw[m * 4 + e2] * ldin(eb2p, e2off + e2 * D_ + n, wbf);
          *cp = v + badd;
        } else {
          *cp += v;
        }
      }
    }
  }
}

// ---------------- attention: one block per (b, h, 4 queries), exact softmax ----------
__global__ __launch_bounds__(256) void attn_kernel(const float* __restrict__ qkv,
                                                   float* __restrict__ o) {
  constexpr int QB = 4;
  int tid = threadIdx.x;
  int qb = blockIdx.x % (S_ / QB);
  int hh = (blockIdx.x / (S_ / QB)) % H_;
  int b  = blockIdx.x / ((S_ / QB) * H_);
  int q0 = qb * QB;
  __shared__ float qv[QB][64];
  __shared__ float sc[QB][S_];
  __shared__ float red[256];
  {
    int qi = tid >> 6, i = tid & 63;
    qv[qi][i] = qkv[(size_t)(b * S_ + q0 + qi) * D3_ + hh * 64 + i];
  }
  __syncthreads();
  for (int j = tid; j < S_; j += 256) {
    const float* kr = qkv + (size_t)(b * S_ + j) * D3_ + D_ + hh * 64;
    float d0 = 0, d1 = 0, d2 = 0, d3 = 0;
#pragma unroll
    for (int i = 0; i < 64; i += 4) {
      float4 k4 = *(const float4*)(kr + i);
      d0 += qv[0][i] * k4.x + qv[0][i + 1] * k4.y + qv[0][i + 2] * k4.z + qv[0][i + 3] * k4.w;
      d1 += qv[1][i] * k4.x + qv[1][i + 1] * k4.y + qv[1][i + 2] * k4.z + qv[1][i + 3] * k4.w;
      d2 += qv[2][i] * k4.x + qv[2][i + 1] * k4.y + qv[2][i + 2] * k4.z + qv[2][i + 3] * k4.w;
      d3 += qv[3][i] * k4.x + qv[3][i + 1] * k4.y + qv[3][i + 2] * k4.z + qv[3][i + 3] * k4.w;
    }
    sc[0][j] = d0 * 0.125f; sc[1][j] = d1 * 0.125f;
    sc[2][j] = d2 * 0.125f; sc[3][j] = d3 * 0.125f;
  }
  __syncthreads();
  float inv[QB];
  for (int qi = 0; qi < QB; qi++) {
    float lmax = -1e30f;
    for (int j = tid; j < S_; j += 256) lmax = fmaxf(lmax, sc[qi][j]);
    red[tid] = lmax; __syncthreads();
    for (int w = 128; w; w >>= 1) { if (tid < w) red[tid] = fmaxf(red[tid], red[tid + w]); __syncthreads(); }
    float mx = red[0]; __syncthreads();
    float ls = 0.f;
    for (int j = tid; j < S_; j += 256) { float e = __expf(sc[qi][j] - mx); sc[qi][j] = e; ls += e; }
    red[tid] = ls; __syncthreads();
    for (int w = 128; w; w >>= 1) { if (tid < w) red[tid] += red[tid + w]; __syncthreads(); }
    inv[qi] = 1.f / red[0]; __syncthreads();
  }
  int d = tid & 63, p = tid >> 6;
  float acc[QB] = {0, 0, 0, 0};
  for (int j = p; j < S_; j += 4) {
    float vv = qkv[(size_t)(b * S_ + j) * D3_ + 2 * D_ + hh * 64 + d];
    acc[0] += sc[0][j] * vv; acc[1] += sc[1][j] * vv;
    acc[2] += sc[2][j] * vv; acc[3] += sc[3][j] * vv;
  }
  for (int qi = 0; qi < QB; qi++) {
    red[tid] = acc[qi]; __syncthreads();
    if (tid < 64) {
      float r = (red[tid] + red[tid + 64] + red[tid + 128] + red[tid + 192]) * inv[qi];
      o[(size_t)(b * S_ + q0 + qi) * D_ + hh * 64 + tid] = r;
    }
    __syncthreads();
  }
}

// ---------------- residual add + LayerNorm (in-place on h) ----------------
__global__ __launch_bounds__(256) void add_ln_kernel(float* __restrict__ h,
                                                     const float* __restrict__ o,
                                                     const void* __restrict__ g,
                                                     const void* __restrict__ beta,
                                                     size_t off,
                                                     const int* __restrict__ flag) {
  const int bf = flag[0];
  int t = blockIdx.x, tid = threadIdx.x;
  __shared__ float r1[256], r2[256];
  float* hr = h + (size_t)t * D_;
  const float* orr = o + (size_t)t * D_;
  float v0 = hr[tid] + orr[tid];
  float v1 = hr[tid + 256] + orr[tid + 256];
  r1[tid] = v0 + v1;
  r2[tid] = v0 * v0 + v1 * v1;
  __syncthreads();
  for (int w = 128; w; w >>= 1) { if (tid < w) { r1[tid] += r1[tid + w]; r2[tid] += r2[tid + w]; } __syncthreads(); }
  float mean = r1[0] * (1.f / D_);
  float var  = r2[0] * (1.f / D_) - mean * mean;
  float rstd = rsqrtf(var + 1e-5f);
  hr[tid]       = (v0 - mean) * rstd * ldin(g, off + tid, bf) + ldin(beta, off + tid, bf);
  hr[tid + 256] = (v1 - mean) * rstd * ldin(g, off + tid + 256, bf) + ldin(beta, off + tid + 256, bf);
}

// ---------------- MoE gating: softmax over E=4, top-2, renormalize ----------------
__global__ __launch_bounds__(256) void gate_kernel(const float* __restrict__ hbuf,
                                                   const void* __restrict__ gw, size_t gwoff,
                                                   const void* __restrict__ gb, size_t gboff,
                                                   float* __restrict__ cw,
                                                   const int* __restrict__ flag) {
  const int bf = flag[0];
  int lane = threadIdx.x & 63, wv = threadIdx.x >> 6;
  int t = blockIdx.x * 4 + wv;
  const float* xr = hbuf + (size_t)t * D_;
  float a[4] = {0, 0, 0, 0};
  for (int d = lane; d < D_; d += 64) {
    float xv = xr[d];
#pragma unroll
    for (int e = 0; e < 4; e++) a[e] += xv * ldin(gw, gwoff + e * D_ + d, bf);
  }
#pragma unroll
  for (int e = 0; e < 4; e++)
    for (int off = 32; off; off >>= 1) a[e] += __shfl_xor(a[e], off, 64);
  if (lane == 0) {
    float lg[4];
#pragma unroll
    for (int e = 0; e < 4; e++) lg[e] = a[e] + ldin(gb, gboff + e, bf);
    float m = fmaxf(fmaxf(lg[0], lg[1]), fmaxf(lg[2], lg[3]));
    float p[4], s = 0.f;
#pragma unroll
    for (int e = 0; e < 4; e++) { p[e] = __expf(lg[e] - m); s += p[e]; }
#pragma unroll
    for (int e = 0; e < 4; e++) p[e] /= s;
    int i0 = 0;
    for (int e = 1; e < 4; e++) if (p[e] > p[i0]) i0 = e;   // first occurrence on ties
    int i1 = -1;
    for (int e = 0; e < 4; e++) if (e != i0 && (i1 < 0 || p[e] > p[i1])) i1 = e;
    float s2 = p[i0] + p[i1];
    float outw[4] = {0, 0, 0, 0};
    outw[i0] = p[i0] / s2;
    outw[i1] = p[i1] / s2;
#pragma unroll
    for (int e = 0; e < 4; e++) cw[t * 4 + e] = outw[e];
  }
}

// ---------------- head: out[b,q] = dot(h[b,-1,:], hw[q,:]) + hb[q] ----------------
__global__ __launch_bounds__(256) void head_kernel(const float* __restrict__ hbuf,
                                                   const void* __restrict__ hw,
                                                   const void* __restrict__ hb,
                                                   void* __restrict__ out,
                                                   const int* __restrict__ flag) {
  const int bf = flag[0];
  int bq = blockIdx.x, tid = threadIdx.x;
  int b = bq / 3, q = bq % 3;
  __shared__ float red[256];
  const float* xr = hbuf + (size_t)(b * S_ + (S_ - 1)) * D_;
  float sacc = xr[tid] * ldin(hw, (size_t)q * D_ + tid, bf)
             + xr[tid + 256] * ldin(hw, (size_t)q * D_ + tid + 256, bf);
  red[tid] = sacc; __syncthreads();
  for (int w = 128; w; w >>= 1) { if (tid < w) red[tid] += red[tid + w]; __syncthreads(); }
  if (tid == 0) {
    float r = red[0] + ldin(hb, q, bf);
    if (bf) ((bf16*)out)[bq] = __float2bfloat16(r);
    else    ((float*)out)[bq] = r;
  }
}

extern "C" void kernel_launch(void* const* d_in, const int* in_sizes, int n_in,
                              void* d_out, int out_size, void* d_ws, size_t ws_size,
                              hipStream_t stream) {
  const void* x    = d_in[0];
  const void* Wp   = d_in[1];
  const void* bp   = d_in[2];
  const void* femb = d_in[3];
  const void* qkvw = d_in[4];
  const void* qkvb = d_in[5];
  const void* ow   = d_in[6];
  const void* ob   = d_in[7];
  const void* g1   = d_in[8];
  const void* be1  = d_in[9];
  const void* gw   = d_in[10];
  const void* gb   = d_in[11];
  const void* ew1  = d_in[12];
  const void* eb1  = d_in[13];
  const void* ew2  = d_in[14];
  const void* eb2  = d_in[15];
  const void* g2   = d_in[16];
  const void* be2  = d_in[17];
  const void* hw   = d_in[18];
  const void* hb   = d_in[19];
  const int*  freq = (const int*)d_in[20];

  // workspace layout (fp32 words): ~101 MB peak
  int*   flag = (int*)d_ws;
  float* xn   = (float*)d_ws + 64;                  // 65536
  float* h    = xn + 65536;                         // T*D
  float* qkv  = h + (size_t)T_ * D_;                // T*3D (aliased by hid_e in MoE phase)
  float* ao   = qkv + (size_t)T_ * D3_;             // T*D
  float* obuf = ao + (size_t)T_ * D_;               // T*D
  float* cw   = obuf + (size_t)T_ * D_;             // T*E
  bf16*  hid  = (bf16*)qkv;                         // T*1024 bf16 = 16 MB, inside qkv region

  detect_kernel<<<1, 64, 0, stream>>>(x, flag);
  instnorm_kernel<<<B_ * F_, 256, 0, stream>>>(x, xn, flag);
  input_proj_kernel<<<(T_ * D_) / 256, 256, 0, stream>>>(xn, Wp, bp, femb, freq, h, flag);

  for (int l = 0; l < 3; l++) {
    // QKV projection: [T,D] @ [3D,D]^T
    gemm_kernel<0><<<dim3(D3_ / 64, T_ / 64), 256, 0, stream>>>(
        h, qkvw, (size_t)l * D3_ * D_, qkvb, (size_t)l * D3_, qkv,
        D3_, D_, D_, D3_, nullptr, nullptr, 0, 0, flag);
    attn_kernel<<<B_ * H_ * (S_ / 4), 256, 0, stream>>>(qkv, ao);
    // output projection
    gemm_kernel<0><<<dim3(D_ / 64, T_ / 64), 256, 0, stream>>>(
        ao, ow, (size_t)l * D_ * D_, ob, (size_t)l * D_, obuf,
        D_, D_, D_, D_, nullptr, nullptr, 0, 0, flag);
    add_ln_kernel<<<T_, 256, 0, stream>>>(h, obuf, g1, be1, (size_t)l * D_, flag);
    gate_kernel<<<T_ / 4, 256, 0, stream>>>(h, gw, (size_t)l * E_ * D_, gb, (size_t)l * E_, cw, flag);
    // dense per-expert MoE (hid_e reuses the dead qkv region)
    for (int e = 0; e < E_; e++) {
      // mat1_e: hid = cw[:,e] * relu(h @ ew1[l,e]^T + eb1[l,e])   [T,1024] bf16
      gemm_kernel<1><<<dim3(1024 / 64, T_ / 64), 256, 0, stream>>>(
          h, ew1, ((size_t)l * E_ + e) * 1024 * 512, eb1, ((size_t)l * E_ + e) * 1024, hid,
          1024, D_, D_, 1024, cw, nullptr, 0, e, flag);
      // mat2_e: obuf (+)= hid @ ew2[l,e]^T (+ weighted eb2 on e==0)   [T,512] fp32
      gemm_kernel<2><<<dim3(D_ / 64, T_ / 64), 256, 0, stream>>>(
          hid, ew2, ((size_t)l * E_ + e) * 512 * 1024, nullptr, 0, obuf,
          D_, 1024, 1024, D_, cw, eb2, (size_t)l * E_ * D_, e, flag);
    }
    add_ln_kernel<<<T_, 256, 0, stream>>>(h, obuf, g2, be2, (size_t)l * D_, flag);
  }

  head_kernel<<<24, 256, 0, stream>>>(h, hw, hb, d_out, flag);
}

// Round 3
// 5582.166 us; speedup vs baseline: 3.5836x; 3.5836x over previous
//
#include <hip/hip_runtime.h>
#include <hip/hip_bf16.h>
#include <math.h>

typedef __hip_bfloat16 bf16;

constexpr int B_ = 8, S_ = 1024, F_ = 8, D_ = 512, H_ = 8, E_ = 4;
constexpr int T_  = B_ * S_;       // 8192 tokens
constexpr int D3_ = 3 * D_;        // 1536

__device__ __forceinline__ float b2f(bf16 v) { return __bfloat162float(v); }
// flag-dispatched input load: bf=1 -> bf16, bf=0 -> fp32 (wave-uniform branch)
__device__ __forceinline__ float ldin(const void* p, size_t i, int bf) {
  return bf ? __bfloat162float(((const bf16*)p)[i]) : ((const float*)p)[i];
}

// ---------------- dtype detector: writes flag[0]=1 if inputs are bf16 ----------------
__global__ void detect_kernel(const void* __restrict__ x, int* __restrict__ flag) {
  if (threadIdx.x == 0 && blockIdx.x == 0) {
    const unsigned short* u = (const unsigned short*)x;
    int c = 0;
    for (int i = 0; i < 256; i += 2) {
      int ex = (u[i] >> 7) & 0xFF;
      if (ex >= 96 && ex <= 144) c++;
    }
    flag[0] = (c >= 64) ? 1 : 0;
  }
}

// ---------------- instance norm over time axis (ddof=1, eps on std) ----------------
__global__ __launch_bounds__(256) void instnorm_kernel(const void* __restrict__ x,
                                                       float* __restrict__ xn,
                                                       const int* __restrict__ flag) {
  const int bf = flag[0];
  int b = blockIdx.x / F_, f = blockIdx.x % F_;
  int tid = threadIdx.x;
  __shared__ float red[256];
  const int base = b * S_ * F_ + f;
  float s = 0.f;
  for (int j = tid; j < S_; j += 256) s += ldin(x, base + j * F_, bf);
  red[tid] = s; __syncthreads();
  for (int w = 128; w; w >>= 1) { if (tid < w) red[tid] += red[tid + w]; __syncthreads(); }
  float mean = red[0] / S_;
  __syncthreads();
  float v = 0.f;
  for (int j = tid; j < S_; j += 256) { float d = ldin(x, base + j * F_, bf) - mean; v += d * d; }
  red[tid] = v; __syncthreads();
  for (int w = 128; w; w >>= 1) { if (tid < w) red[tid] += red[tid + w]; __syncthreads(); }
  float inv = 1.f / (sqrtf(red[0] / (float)(S_ - 1)) + 1e-5f);
  for (int j = tid; j < S_; j += 256) xn[base + j * F_] = (ldin(x, base + j * F_, bf) - mean) * inv;
}

// ---------------- input projection + freq emb + positional encoding ----------------
__global__ __launch_bounds__(256) void input_proj_kernel(const float* __restrict__ xn,
                                                         const void* __restrict__ Wp,
                                                         const void* __restrict__ bp,
                                                         const void* __restrict__ femb,
                                                         const int* __restrict__ freq_idx,
                                                         float* __restrict__ h,
                                                         const int* __restrict__ flag) {
  const int bf = flag[0];
  int idx = blockIdx.x * 256 + threadIdx.x;   // < T_*D_
  int d = idx % D_;
  int t = idx / D_;
  int s = t % S_;
  int fi = freq_idx[0];
  float acc = ldin(bp, d, bf) + ldin(femb, (size_t)fi * D_ + d, bf);
  int i2 = d & ~1;
  const float cexp = -9.2103403719761836f / (float)D_;   // -ln(10000)/D
  float ang = (float)s * expf((float)i2 * cexp);
  acc += (d & 1) ? cosf(ang) : sinf(ang);
  const float* xr = xn + t * F_;
#pragma unroll
  for (int f = 0; f < F_; f++) acc += xr[f] * ldin(Wp, (size_t)d * F_ + f, bf);
  h[idx] = acc;
}

// ---------------- generic tiled GEMM: C[m,n] = sum_k A[m,k] * W[n,k] (+epilogue) -----
// MODE 0: A fp32, C fp32, +bias
// MODE 1: A fp32, C bf16, c = cw[m*4+eidx] * relu(acc + bias[n])  (MoE mat1, expert eidx)
// MODE 2: A bf16 (hid_e), C fp32;
//         eidx==0: C = acc + sum_e cw[m*4+e]*eb2[e*D+n]; else C += acc (MoE mat2)
template <int MODE>
__global__ __launch_bounds__(256) void gemm_kernel(
    const void* __restrict__ A_, const void* __restrict__ Wt, size_t woff,
    const void* __restrict__ bias, size_t boff, void* __restrict__ C_,
    int N, int Kd, int lda, int ldc,
    const float* __restrict__ cw, const void* __restrict__ eb2p, size_t e2off,
    int eidx, const int* __restrict__ flag) {
  const int wbf = flag[0];
  constexpr int BK = 16;
  __shared__ __align__(16) float As[BK][68];
  __shared__ __align__(16) float Ws[BK][68];
  int tid = threadIdx.x;
  int tx = tid & 15, ty = tid >> 4;
  int n0 = blockIdx.x * 64;
  int m0 = blockIdx.y * 64;
  int lk = tid & 15;         // k within tile
  int lm = tid >> 4;         // row group
  float acc[4][4] = {};
  for (int k0 = 0; k0 < Kd; k0 += BK) {
    int k = k0 + lk;
#pragma unroll
    for (int p = 0; p < 4; p++) {
      int mm = lm + p * 16;
      float av = (MODE == 2) ? b2f(((const bf16*)A_)[(size_t)(m0 + mm) * lda + k])
                             : ((const float*)A_)[(size_t)(m0 + mm) * lda + k];
      As[lk][mm] = av;
      int nn = lm + p * 16;
      Ws[lk][nn] = ldin(Wt, woff + (size_t)(n0 + nn) * Kd + k, wbf);
    }
    __syncthreads();
#pragma unroll
    for (int kk = 0; kk < BK; kk++) {
      float4 a4 = *(const float4*)&As[kk][ty * 4];
      float4 b4 = *(const float4*)&Ws[kk][tx * 4];
      float aa[4] = {a4.x, a4.y, a4.z, a4.w};
      float bb[4] = {b4.x, b4.y, b4.z, b4.w};
#pragma unroll
      for (int i = 0; i < 4; i++)
#pragma unroll
        for (int j = 0; j < 4; j++) acc[i][j] += aa[i] * bb[j];
    }
    __syncthreads();
  }
#pragma unroll
  for (int i = 0; i < 4; i++) {
    int m = m0 + ty * 4 + i;
#pragma unroll
    for (int j = 0; j < 4; j++) {
      int n = n0 + tx * 4 + j;
      float v = acc[i][j];
      if (MODE == 0) {
        ((float*)C_)[(size_t)m * ldc + n] = v + ldin(bias, boff + n, wbf);
      } else if (MODE == 1) {
        v += ldin(bias, boff + n, wbf);
        ((bf16*)C_)[(size_t)m * ldc + n] =
            __float2bfloat16(fmaxf(v, 0.f) * cw[m * 4 + eidx]);
      } else {
        float* cp = (float*)C_ + (size_t)m * ldc + n;
        if (eidx == 0) {
          float badd = 0.f;
#pragma unroll
          for (int e2 = 0; e2 < 4; e2++)
            badd += cw[m * 4 + e2] * ldin(eb2p, e2off + e2 * D_ + n, wbf);
          *cp = v + badd;
        } else {
          *cp += v;
        }
      }
    }
  }
}

// ---------------- flash-style attention: one block per (b, h, 64-query tile) --------
// Online softmax; S-tile and PV both computed as 64x64x64 register-blocked GEMMs.
// LDS: Qs [d][q] (persistent), KVs = K [d][k] then V [k][d], Ps = P [q][k]. 52 KB.
__global__ __launch_bounds__(256) void attn_kernel(const float* __restrict__ qkv,
                                                   float* __restrict__ o) {
  __shared__ __align__(16) float Qs[64][68];
  __shared__ __align__(16) float KVs[64][68];
  __shared__ __align__(16) float Ps[64][68];
  int tid = threadIdx.x;
  int qt = blockIdx.x & 15;
  int hh = (blockIdx.x >> 4) & 7;
  int b  = blockIdx.x >> 7;
  int q0 = qt * 64;
  int tx = tid & 15, ty = tid >> 4;
  int sr = tid >> 2;               // staging row 0..63
  int sc0 = (tid & 3) * 16;        // staging col base

  // stage Q transposed: Qs[d][q]
  {
    const float* src = qkv + (size_t)(b * S_ + q0 + sr) * D3_ + hh * 64 + sc0;
#pragma unroll
    for (int u = 0; u < 4; u++) {
      float4 v4 = *(const float4*)(src + u * 4);
      Qs[sc0 + u * 4 + 0][sr] = v4.x;
      Qs[sc0 + u * 4 + 1][sr] = v4.y;
      Qs[sc0 + u * 4 + 2][sr] = v4.z;
      Qs[sc0 + u * 4 + 3][sr] = v4.w;
    }
  }
  float m[4] = {-1e30f, -1e30f, -1e30f, -1e30f};
  float l[4] = {0.f, 0.f, 0.f, 0.f};
  float acc[4][4] = {};

  for (int kt = 0; kt < 16; kt++) {
    int k0 = kt * 64;
    // stage K transposed: KVs[d][k]
    {
      const float* src = qkv + (size_t)(b * S_ + k0 + sr) * D3_ + D_ + hh * 64 + sc0;
#pragma unroll
      for (int u = 0; u < 4; u++) {
        float4 v4 = *(const float4*)(src + u * 4);
        KVs[sc0 + u * 4 + 0][sr] = v4.x;
        KVs[sc0 + u * 4 + 1][sr] = v4.y;
        KVs[sc0 + u * 4 + 2][sr] = v4.z;
        KVs[sc0 + u * 4 + 3][sr] = v4.w;
      }
    }
    __syncthreads();
    // S tile: s[i][j] = sum_d Q[q0+ty*4+i][d] * K[k0+tx*4+j][d]
    float s[4][4] = {};
#pragma unroll 8
    for (int dd = 0; dd < 64; dd++) {
      float4 a4 = *(const float4*)&Qs[dd][ty * 4];
      float4 b4 = *(const float4*)&KVs[dd][tx * 4];
      float aa[4] = {a4.x, a4.y, a4.z, a4.w};
      float bb[4] = {b4.x, b4.y, b4.z, b4.w};
#pragma unroll
      for (int i = 0; i < 4; i++)
#pragma unroll
        for (int j = 0; j < 4; j++) s[i][j] += aa[i] * bb[j];
    }
    __syncthreads();   // K reads done; KVs is now free for V
    // online softmax update (rows q = ty*4+i live across the 16-lane tx group)
    float pr[4][4];
#pragma unroll
    for (int i = 0; i < 4; i++) {
      float rm = fmaxf(fmaxf(s[i][0], s[i][1]), fmaxf(s[i][2], s[i][3])) * 0.125f;
#pragma unroll
      for (int off = 8; off; off >>= 1) rm = fmaxf(rm, __shfl_xor(rm, off, 64));
      float mnew = fmaxf(m[i], rm);
      float alpha = __expf(m[i] - mnew);
      m[i] = mnew;
      float rs = 0.f;
#pragma unroll
      for (int j = 0; j < 4; j++) {
        float p = __expf(s[i][j] * 0.125f - mnew);
        pr[i][j] = p;
        rs += p;
      }
#pragma unroll
      for (int off = 8; off; off >>= 1) rs += __shfl_xor(rs, off, 64);
      l[i] = l[i] * alpha + rs;
#pragma unroll
      for (int j = 0; j < 4; j++) acc[i][j] *= alpha;
      // write P row to LDS: Ps[q][k]
      *(float4*)&Ps[ty * 4 + i][tx * 4] = make_float4(pr[i][0], pr[i][1], pr[i][2], pr[i][3]);
    }
    // stage V row-major into KVs: KVs[k][d]
    {
      const float* src = qkv + (size_t)(b * S_ + k0 + sr) * D3_ + 2 * D_ + hh * 64 + sc0;
#pragma unroll
      for (int u = 0; u < 4; u++)
        *(float4*)&KVs[sr][sc0 + u * 4] = *(const float4*)(src + u * 4);
    }
    __syncthreads();
    // PV: acc[i][j] += sum_k P[q][k] * V[k][d=tx*4+j]
#pragma unroll 8
    for (int kk = 0; kk < 64; kk++) {
      float4 v4 = *(const float4*)&KVs[kk][tx * 4];
      float vv[4] = {v4.x, v4.y, v4.z, v4.w};
#pragma unroll
      for (int i = 0; i < 4; i++) {
        float p = Ps[ty * 4 + i][kk];
#pragma unroll
        for (int j = 0; j < 4; j++) acc[i][j] += p * vv[j];
      }
    }
    __syncthreads();   // Ps/KVs reads done before next iteration overwrites
  }
  // epilogue: O[q][d] = acc / l
#pragma unroll
  for (int i = 0; i < 4; i++) {
    float inv = 1.f / l[i];
    float4 r = make_float4(acc[i][0] * inv, acc[i][1] * inv, acc[i][2] * inv, acc[i][3] * inv);
    *(float4*)&o[(size_t)(b * S_ + q0 + ty * 4 + i) * D_ + hh * 64 + tx * 4] = r;
  }
}

// ---------------- residual add + LayerNorm (in-place on h) ----------------
__global__ __launch_bounds__(256) void add_ln_kernel(float* __restrict__ h,
                                                     const float* __restrict__ o,
                                                     const void* __restrict__ g,
                                                     const void* __restrict__ beta,
                                                     size_t off,
                                                     const int* __restrict__ flag) {
  const int bf = flag[0];
  int t = blockIdx.x, tid = threadIdx.x;
  __shared__ float r1[256], r2[256];
  float* hr = h + (size_t)t * D_;
  const float* orr = o + (size_t)t * D_;
  float v0 = hr[tid] + orr[tid];
  float v1 = hr[tid + 256] + orr[tid + 256];
  r1[tid] = v0 + v1;
  r2[tid] = v0 * v0 + v1 * v1;
  __syncthreads();
  for (int w = 128; w; w >>= 1) { if (tid < w) { r1[tid] += r1[tid + w]; r2[tid] += r2[tid + w]; } __syncthreads(); }
  float mean = r1[0] * (1.f / D_);
  float var  = r2[0] * (1.f / D_) - mean * mean;
  float rstd = rsqrtf(var + 1e-5f);
  hr[tid]       = (v0 - mean) * rstd * ldin(g, off + tid, bf) + ldin(beta, off + tid, bf);
  hr[tid + 256] = (v1 - mean) * rstd * ldin(g, off + tid + 256, bf) + ldin(beta, off + tid + 256, bf);
}

// ---------------- MoE gating: softmax over E=4, top-2, renormalize ----------------
__global__ __launch_bounds__(256) void gate_kernel(const float* __restrict__ hbuf,
                                                   const void* __restrict__ gw, size_t gwoff,
                                                   const void* __restrict__ gb, size_t gboff,
                                                   float* __restrict__ cw,
                                                   const int* __restrict__ flag) {
  const int bf = flag[0];
  int lane = threadIdx.x & 63, wv = threadIdx.x >> 6;
  int t = blockIdx.x * 4 + wv;
  const float* xr = hbuf + (size_t)t * D_;
  float a[4] = {0, 0, 0, 0};
  for (int d = lane; d < D_; d += 64) {
    float xv = xr[d];
#pragma unroll
    for (int e = 0; e < 4; e++) a[e] += xv * ldin(gw, gwoff + e * D_ + d, bf);
  }
#pragma unroll
  for (int e = 0; e < 4; e++)
    for (int off = 32; off; off >>= 1) a[e] += __shfl_xor(a[e], off, 64);
  if (lane == 0) {
    float lg[4];
#pragma unroll
    for (int e = 0; e < 4; e++) lg[e] = a[e] + ldin(gb, gboff + e, bf);
    float m = fmaxf(fmaxf(lg[0], lg[1]), fmaxf(lg[2], lg[3]));
    float p[4], s = 0.f;
#pragma unroll
    for (int e = 0; e < 4; e++) { p[e] = __expf(lg[e] - m); s += p[e]; }
#pragma unroll
    for (int e = 0; e < 4; e++) p[e] /= s;
    int i0 = 0;
    for (int e = 1; e < 4; e++) if (p[e] > p[i0]) i0 = e;   // first occurrence on ties
    int i1 = -1;
    for (int e = 0; e < 4; e++) if (e != i0 && (i1 < 0 || p[e] > p[i1])) i1 = e;
    float s2 = p[i0] + p[i1];
    float outw[4] = {0, 0, 0, 0};
    outw[i0] = p[i0] / s2;
    outw[i1] = p[i1] / s2;
#pragma unroll
    for (int e = 0; e < 4; e++) cw[t * 4 + e] = outw[e];
  }
}

// ---------------- head: out[b,q] = dot(h[b,-1,:], hw[q,:]) + hb[q] ----------------
__global__ __launch_bounds__(256) void head_kernel(const float* __restrict__ hbuf,
                                                   const void* __restrict__ hw,
                                                   const void* __restrict__ hb,
                                                   void* __restrict__ out,
                                                   const int* __restrict__ flag) {
  const int bf = flag[0];
  int bq = blockIdx.x, tid = threadIdx.x;
  int b = bq / 3, q = bq % 3;
  __shared__ float red[256];
  const float* xr = hbuf + (size_t)(b * S_ + (S_ - 1)) * D_;
  float sacc = xr[tid] * ldin(hw, (size_t)q * D_ + tid, bf)
             + xr[tid + 256] * ldin(hw, (size_t)q * D_ + tid + 256, bf);
  red[tid] = sacc; __syncthreads();
  for (int w = 128; w; w >>= 1) { if (tid < w) red[tid] += red[tid + w]; __syncthreads(); }
  if (tid == 0) {
    float r = red[0] + ldin(hb, q, bf);
    if (bf) ((bf16*)out)[bq] = __float2bfloat16(r);
    else    ((float*)out)[bq] = r;
  }
}

extern "C" void kernel_launch(void* const* d_in, const int* in_sizes, int n_in,
                              void* d_out, int out_size, void* d_ws, size_t ws_size,
                              hipStream_t stream) {
  const void* x    = d_in[0];
  const void* Wp   = d_in[1];
  const void* bp   = d_in[2];
  const void* femb = d_in[3];
  const void* qkvw = d_in[4];
  const void* qkvb = d_in[5];
  const void* ow   = d_in[6];
  const void* ob   = d_in[7];
  const void* g1   = d_in[8];
  const void* be1  = d_in[9];
  const void* gw   = d_in[10];
  const void* gb   = d_in[11];
  const void* ew1  = d_in[12];
  const void* eb1  = d_in[13];
  const void* ew2  = d_in[14];
  const void* eb2  = d_in[15];
  const void* g2   = d_in[16];
  const void* be2  = d_in[17];
  const void* hw   = d_in[18];
  const void* hb   = d_in[19];
  const int*  freq = (const int*)d_in[20];

  // workspace layout (fp32 words): ~101 MB peak
  int*   flag = (int*)d_ws;
  float* xn   = (float*)d_ws + 64;                  // 65536
  float* h    = xn + 65536;                         // T*D
  float* qkv  = h + (size_t)T_ * D_;                // T*3D (aliased by hid_e in MoE phase)
  float* ao   = qkv + (size_t)T_ * D3_;             // T*D
  float* obuf = ao + (size_t)T_ * D_;               // T*D
  float* cw   = obuf + (size_t)T_ * D_;             // T*E
  bf16*  hid  = (bf16*)qkv;                         // T*1024 bf16 = 16 MB, inside qkv region

  detect_kernel<<<1, 64, 0, stream>>>(x, flag);
  instnorm_kernel<<<B_ * F_, 256, 0, stream>>>(x, xn, flag);
  input_proj_kernel<<<(T_ * D_) / 256, 256, 0, stream>>>(xn, Wp, bp, femb, freq, h, flag);

  for (int l = 0; l < 3; l++) {
    // QKV projection: [T,D] @ [3D,D]^T
    gemm_kernel<0><<<dim3(D3_ / 64, T_ / 64), 256, 0, stream>>>(
        h, qkvw, (size_t)l * D3_ * D_, qkvb, (size_t)l * D3_, qkv,
        D3_, D_, D_, D3_, nullptr, nullptr, 0, 0, flag);
    attn_kernel<<<B_ * H_ * (S_ / 64), 256, 0, stream>>>(qkv, ao);
    // output projection
    gemm_kernel<0><<<dim3(D_ / 64, T_ / 64), 256, 0, stream>>>(
        ao, ow, (size_t)l * D_ * D_, ob, (size_t)l * D_, obuf,
        D_, D_, D_, D_, nullptr, nullptr, 0, 0, flag);
    add_ln_kernel<<<T_, 256, 0, stream>>>(h, obuf, g1, be1, (size_t)l * D_, flag);
    gate_kernel<<<T_ / 4, 256, 0, stream>>>(h, gw, (size_t)l * E_ * D_, gb, (size_t)l * E_, cw, flag);
    // dense per-expert MoE (hid_e reuses the dead qkv region)
    for (int e = 0; e < E_; e++) {
      // mat1_e: hid = cw[:,e] * relu(h @ ew1[l,e]^T + eb1[l,e])   [T,1024] bf16
      gemm_kernel<1><<<dim3(1024 / 64, T_ / 64), 256, 0, stream>>>(
          h, ew1, ((size_t)l * E_ + e) * 1024 * 512, eb1, ((size_t)l * E_ + e) * 1024, hid,
          1024, D_, D_, 1024, cw, nullptr, 0, e, flag);
      // mat2_e: obuf (+)= hid @ ew2[l,e]^T (+ weighted eb2 on e==0)   [T,512] fp32
      gemm_kernel<2><<<dim3(D_ / 64, T_ / 64), 256, 0, stream>>>(
          hid, ew2, ((size_t)l * E_ + e) * 512 * 1024, nullptr, 0, obuf,
          D_, 1024, 1024, D_, cw, eb2, (size_t)l * E_ * D_, e, flag);
    }
    add_ln_kernel<<<T_, 256, 0, stream>>>(h, obuf, g2, be2, (size_t)l * D_, flag);
  }

  head_kernel<<<24, 256, 0, stream>>>(h, hw, hb, d_out, flag);
}

// Round 4
// 2249.979 us; speedup vs baseline: 8.8910x; 2.4810x over previous
//
#include <hip/hip_runtime.h>
#include <hip/hip_bf16.h>
#include <math.h>

typedef __hip_bfloat16 bf16;
typedef __attribute__((ext_vector_type(8))) short short8;   // 8 bf16 (4 VGPRs)
typedef __attribute__((ext_vector_type(4))) float f32x4;

constexpr int B_ = 8, S_ = 1024, F_ = 8, D_ = 512, H_ = 8, E_ = 4;
constexpr int T_  = B_ * S_;       // 8192 tokens
constexpr int D3_ = 3 * D_;        // 1536

__device__ __forceinline__ float b2f(bf16 v) { return __bfloat162float(v); }
// flag-dispatched input load: bf=1 -> bf16, bf=0 -> fp32 (wave-uniform branch)
__device__ __forceinline__ float ldin(const void* p, size_t i, int bf) {
  return bf ? __bfloat162float(((const bf16*)p)[i]) : ((const float*)p)[i];
}
// async global->LDS, 16 B per lane; lds dest = wave-uniform base + lane*16
__device__ __forceinline__ void gload16(const void* g, void* l) {
  __builtin_amdgcn_global_load_lds((const __attribute__((address_space(1))) unsigned int*)g,
                                   (__attribute__((address_space(3))) unsigned int*)l, 16, 0, 0);
}

// ---------------- dtype detector: writes flag[0]=1 if inputs are bf16 ----------------
__global__ void detect_kernel(const void* __restrict__ x, int* __restrict__ flag) {
  if (threadIdx.x == 0 && blockIdx.x == 0) {
    const unsigned short* u = (const unsigned short*)x;
    int c = 0;
    for (int i = 0; i < 256; i += 2) {
      int ex = (u[i] >> 7) & 0xFF;
      if (ex >= 96 && ex <= 144) c++;
    }
    flag[0] = (c >= 64) ? 1 : 0;
  }
}

// ---------------- instance norm over time axis (ddof=1, eps on std) ----------------
__global__ __launch_bounds__(256) void instnorm_kernel(const void* __restrict__ x,
                                                       float* __restrict__ xn,
                                                       const int* __restrict__ flag) {
  const int bf = flag[0];
  int b = blockIdx.x / F_, f = blockIdx.x % F_;
  int tid = threadIdx.x;
  __shared__ float red[256];
  const int base = b * S_ * F_ + f;
  float s = 0.f;
  for (int j = tid; j < S_; j += 256) s += ldin(x, base + j * F_, bf);
  red[tid] = s; __syncthreads();
  for (int w = 128; w; w >>= 1) { if (tid < w) red[tid] += red[tid + w]; __syncthreads(); }
  float mean = red[0] / S_;
  __syncthreads();
  float v = 0.f;
  for (int j = tid; j < S_; j += 256) { float d = ldin(x, base + j * F_, bf) - mean; v += d * d; }
  red[tid] = v; __syncthreads();
  for (int w = 128; w; w >>= 1) { if (tid < w) red[tid] += red[tid + w]; __syncthreads(); }
  float inv = 1.f / (sqrtf(red[0] / (float)(S_ - 1)) + 1e-5f);
  for (int j = tid; j < S_; j += 256) xn[base + j * F_] = (ldin(x, base + j * F_, bf) - mean) * inv;
}

// ---------------- input projection + freq emb + positional encoding ----------------
__global__ __launch_bounds__(256) void input_proj_kernel(const float* __restrict__ xn,
                                                         const void* __restrict__ Wp,
                                                         const void* __restrict__ bp,
                                                         const void* __restrict__ femb,
                                                         const int* __restrict__ freq_idx,
                                                         float* __restrict__ h,
                                                         bf16* __restrict__ hb16,
                                                         const int* __restrict__ flag) {
  const int bf = flag[0];
  int idx = blockIdx.x * 256 + threadIdx.x;   // < T_*D_
  int d = idx % D_;
  int t = idx / D_;
  int s = t % S_;
  int fi = freq_idx[0];
  float acc = ldin(bp, d, bf) + ldin(femb, (size_t)fi * D_ + d, bf);
  int i2 = d & ~1;
  const float cexp = -9.2103403719761836f / (float)D_;   // -ln(10000)/D
  float ang = (float)s * expf((float)i2 * cexp);
  acc += (d & 1) ? cosf(ang) : sinf(ang);
  const float* xr = xn + t * F_;
#pragma unroll
  for (int f = 0; f < F_; f++) acc += xr[f] * ldin(Wp, (size_t)d * F_ + f, bf);
  h[idx] = acc;
  hb16[idx] = __float2bfloat16(acc);
}

// ---------------- MFMA GEMM: C[m,n] = sum_k A[m,k] * W[n,k] (+epilogue) ----------------
// 128x128 tile, BK=32, 4 waves x (4x4) mfma_f32_16x16x32_bf16. A is bf16 always.
// W is bf16 (flag=1, global_load_lds path) or fp32 (flag=0, convert-through-register path).
// MODE 0: C fp32 = acc + bias
// MODE 1: C bf16 = cw[m*4+eidx] * relu(acc + bias[n])        (MoE mat1, expert eidx)
// MODE 2: C fp32 (+)= acc; on eidx==0, = acc + sum_e cw*eb2  (MoE mat2, accumulated)
template <int MODE>
__global__ __launch_bounds__(256) void mfma_gemm(
    const bf16* __restrict__ A, const void* __restrict__ Wt, size_t woff,
    const void* __restrict__ bias, size_t boff, void* __restrict__ C_,
    int Kd, int lda, int ldb, int ldc,
    const float* __restrict__ cw, const void* __restrict__ eb2p, size_t e2off,
    int eidx, const int* __restrict__ flag) {
  const int wbf = flag[0];
  __shared__ bf16 As[128][32];
  __shared__ bf16 Bs[128][32];
  const int tid = threadIdx.x;
  const int ln = tid & 63, wv = tid >> 6;
  const int n0 = blockIdx.x * 128;
  const int m0 = blockIdx.y * 128;
  const int wr = (wv >> 1) * 64, wc = (wv & 1) * 64;   // wave quadrant
  const int mrow = ln & 15, quad = ln >> 4;
  const int srow = ln >> 2;          // staging row-in-16 group
  const int skof = (ln & 3) * 8;     // staging k offset (elements)

  f32x4 acc[4][4];
#pragma unroll
  for (int i = 0; i < 4; i++)
#pragma unroll
    for (int j = 0; j < 4; j++) acc[i][j] = (f32x4){0.f, 0.f, 0.f, 0.f};

  for (int k0 = 0; k0 < Kd; k0 += 32) {
    // stage A: 2 x global_load_lds(16B) per thread
#pragma unroll
    for (int j = 0; j < 2; j++) {
      int row = 16 * (4 * j + wv) + srow;
      gload16(A + (size_t)(m0 + row) * lda + k0 + skof,
              (char*)&As[0][0] + (size_t)(4 * j + wv) * 1024);
    }
    if (wbf) {
#pragma unroll
      for (int j = 0; j < 2; j++) {
        int row = 16 * (4 * j + wv) + srow;
        gload16((const bf16*)Wt + woff + (size_t)(n0 + row) * ldb + k0 + skof,
                (char*)&Bs[0][0] + (size_t)(4 * j + wv) * 1024);
      }
    } else {
#pragma unroll
      for (int j = 0; j < 2; j++) {
        int row = 16 * (4 * j + wv) + srow;
        const float* g = (const float*)Wt + woff + (size_t)(n0 + row) * ldb + k0 + skof;
        short8 v;
#pragma unroll
        for (int u = 0; u < 8; u++) {
          bf16 t = __float2bfloat16(g[u]);
          v[u] = *(short*)&t;
        }
        *(short8*)&Bs[row][skof] = v;
      }
    }
    __syncthreads();
    short8 af[4], bfr[4];
#pragma unroll
    for (int t = 0; t < 4; t++) {
      af[t]  = *(const short8*)&As[wr + t * 16 + mrow][quad * 8];
      bfr[t] = *(const short8*)&Bs[wc + t * 16 + mrow][quad * 8];
    }
#pragma unroll
    for (int i = 0; i < 4; i++)
#pragma unroll
      for (int j = 0; j < 4; j++)
        acc[i][j] = __builtin_amdgcn_mfma_f32_16x16x32_bf16(af[i], bfr[j], acc[i][j], 0, 0, 0);
    __syncthreads();
  }

  // epilogue: C/D layout col=lane&15, row=quad*4+reg
#pragma unroll
  for (int tj = 0; tj < 4; tj++) {
    int n = n0 + wc + tj * 16 + mrow;
    float bv = (MODE != 2) ? ldin(bias, boff + n, wbf) : 0.f;
#pragma unroll
    for (int ti = 0; ti < 4; ti++) {
      int mbase = m0 + wr + ti * 16 + quad * 4;
#pragma unroll
      for (int r = 0; r < 4; r++) {
        int m = mbase + r;
        float v = acc[ti][tj][r];
        if (MODE == 0) {
          ((float*)C_)[(size_t)m * ldc + n] = v + bv;
        } else if (MODE == 1) {
          ((bf16*)C_)[(size_t)m * ldc + n] =
              __float2bfloat16(fmaxf(v + bv, 0.f) * cw[m * 4 + eidx]);
        } else {
          float* cp = (float*)C_ + (size_t)m * ldc + n;
          if (eidx == 0) {
            float badd = 0.f;
#pragma unroll
            for (int e2 = 0; e2 < 4; e2++)
              badd += cw[m * 4 + e2] * ldin(eb2p, e2off + e2 * D_ + n, wbf);
            *cp = v + badd;
          } else {
            *cp += v;
          }
        }
      }
    }
  }
}

// ---------------- flash-style attention: one block per (b, h, 64-query tile) --------
// Online softmax; S-tile and PV both 64x64x64 register-blocked GEMMs. O written bf16.
__global__ __launch_bounds__(256) void attn_kernel(const float* __restrict__ qkv,
                                                   bf16* __restrict__ o) {
  __shared__ __align__(16) float Qs[64][68];
  __shared__ __align__(16) float KVs[64][68];
  __shared__ __align__(16) float Ps[64][68];
  int tid = threadIdx.x;
  int qt = blockIdx.x & 15;
  int hh = (blockIdx.x >> 4) & 7;
  int b  = blockIdx.x >> 7;
  int q0 = qt * 64;
  int tx = tid & 15, ty = tid >> 4;
  int sr = tid >> 2;               // staging row 0..63
  int sc0 = (tid & 3) * 16;        // staging col base

  // stage Q transposed: Qs[d][q]
  {
    const float* src = qkv + (size_t)(b * S_ + q0 + sr) * D3_ + hh * 64 + sc0;
#pragma unroll
    for (int u = 0; u < 4; u++) {
      float4 v4 = *(const float4*)(src + u * 4);
      Qs[sc0 + u * 4 + 0][sr] = v4.x;
      Qs[sc0 + u * 4 + 1][sr] = v4.y;
      Qs[sc0 + u * 4 + 2][sr] = v4.z;
      Qs[sc0 + u * 4 + 3][sr] = v4.w;
    }
  }
  float m[4] = {-1e30f, -1e30f, -1e30f, -1e30f};
  float l[4] = {0.f, 0.f, 0.f, 0.f};
  float acc[4][4] = {};

  for (int kt = 0; kt < 16; kt++) {
    int k0 = kt * 64;
    // stage K transposed: KVs[d][k]
    {
      const float* src = qkv + (size_t)(b * S_ + k0 + sr) * D3_ + D_ + hh * 64 + sc0;
#pragma unroll
      for (int u = 0; u < 4; u++) {
        float4 v4 = *(const float4*)(src + u * 4);
        KVs[sc0 + u * 4 + 0][sr] = v4.x;
        KVs[sc0 + u * 4 + 1][sr] = v4.y;
        KVs[sc0 + u * 4 + 2][sr] = v4.z;
        KVs[sc0 + u * 4 + 3][sr] = v4.w;
      }
    }
    __syncthreads();
    // S tile: s[i][j] = sum_d Q[q0+ty*4+i][d] * K[k0+tx*4+j][d]
    float s[4][4] = {};
#pragma unroll 8
    for (int dd = 0; dd < 64; dd++) {
      float4 a4 = *(const float4*)&Qs[dd][ty * 4];
      float4 b4 = *(const float4*)&KVs[dd][tx * 4];
      float aa[4] = {a4.x, a4.y, a4.z, a4.w};
      float bb[4] = {b4.x, b4.y, b4.z, b4.w};
#pragma unroll
      for (int i = 0; i < 4; i++)
#pragma unroll
        for (int j = 0; j < 4; j++) s[i][j] += aa[i] * bb[j];
    }
    __syncthreads();   // K reads done; KVs is now free for V
    // online softmax update (rows q = ty*4+i live across the 16-lane tx group)
    float pr[4][4];
#pragma unroll
    for (int i = 0; i < 4; i++) {
      float rm = fmaxf(fmaxf(s[i][0], s[i][1]), fmaxf(s[i][2], s[i][3])) * 0.125f;
#pragma unroll
      for (int off = 8; off; off >>= 1) rm = fmaxf(rm, __shfl_xor(rm, off, 64));
      float mnew = fmaxf(m[i], rm);
      float alpha = __expf(m[i] - mnew);
      m[i] = mnew;
      float rs = 0.f;
#pragma unroll
      for (int j = 0; j < 4; j++) {
        float p = __expf(s[i][j] * 0.125f - mnew);
        pr[i][j] = p;
        rs += p;
      }
#pragma unroll
      for (int off = 8; off; off >>= 1) rs += __shfl_xor(rs, off, 64);
      l[i] = l[i] * alpha + rs;
#pragma unroll
      for (int j = 0; j < 4; j++) acc[i][j] *= alpha;
      // write P row to LDS: Ps[q][k]
      *(float4*)&Ps[ty * 4 + i][tx * 4] = make_float4(pr[i][0], pr[i][1], pr[i][2], pr[i][3]);
    }
    // stage V row-major into KVs: KVs[k][d]
    {
      const float* src = qkv + (size_t)(b * S_ + k0 + sr) * D3_ + 2 * D_ + hh * 64 + sc0;
#pragma unroll
      for (int u = 0; u < 4; u++)
        *(float4*)&KVs[sr][sc0 + u * 4] = *(const float4*)(src + u * 4);
    }
    __syncthreads();
    // PV: acc[i][j] += sum_k P[q][k] * V[k][d=tx*4+j]  (P read as float4 -> ~no conflicts)
#pragma unroll 4
    for (int kk0 = 0; kk0 < 64; kk0 += 4) {
      float p_[4][4];
#pragma unroll
      for (int i = 0; i < 4; i++) {
        float4 t4 = *(const float4*)&Ps[ty * 4 + i][kk0];
        p_[i][0] = t4.x; p_[i][1] = t4.y; p_[i][2] = t4.z; p_[i][3] = t4.w;
      }
#pragma unroll
      for (int j2 = 0; j2 < 4; j2++) {
        float4 v4 = *(const float4*)&KVs[kk0 + j2][tx * 4];
        float vv[4] = {v4.x, v4.y, v4.z, v4.w};
#pragma unroll
        for (int i = 0; i < 4; i++)
#pragma unroll
          for (int j = 0; j < 4; j++) acc[i][j] += p_[i][j2] * vv[j];
      }
    }
    __syncthreads();   // Ps/KVs reads done before next iteration overwrites
  }
  // epilogue: O[q][d] = acc / l, written bf16 (feeds MFMA O-projection)
#pragma unroll
  for (int i = 0; i < 4; i++) {
    float inv = 1.f / l[i];
    size_t base = (size_t)(b * S_ + q0 + ty * 4 + i) * D_ + hh * 64 + tx * 4;
#pragma unroll
    for (int c = 0; c < 4; c++) o[base + c] = __float2bfloat16(acc[i][c] * inv);
  }
}

// ---------------- residual add + LayerNorm (in-place on h, dual write bf16) ---------
__global__ __launch_bounds__(256) void add_ln_kernel(float* __restrict__ h,
                                                     bf16* __restrict__ hb16,
                                                     const float* __restrict__ o,
                                                     const void* __restrict__ g,
                                                     const void* __restrict__ beta,
                                                     size_t off,
                                                     const int* __restrict__ flag) {
  const int bf = flag[0];
  int t = blockIdx.x, tid = threadIdx.x;
  __shared__ float r1[256], r2[256];
  float* hr = h + (size_t)t * D_;
  const float* orr = o + (size_t)t * D_;
  float v0 = hr[tid] + orr[tid];
  float v1 = hr[tid + 256] + orr[tid + 256];
  r1[tid] = v0 + v1;
  r2[tid] = v0 * v0 + v1 * v1;
  __syncthreads();
  for (int w = 128; w; w >>= 1) { if (tid < w) { r1[tid] += r1[tid + w]; r2[tid] += r2[tid + w]; } __syncthreads(); }
  float mean = r1[0] * (1.f / D_);
  float var  = r2[0] * (1.f / D_) - mean * mean;
  float rstd = rsqrtf(var + 1e-5f);
  float o0 = (v0 - mean) * rstd * ldin(g, off + tid, bf) + ldin(beta, off + tid, bf);
  float o1 = (v1 - mean) * rstd * ldin(g, off + tid + 256, bf) + ldin(beta, off + tid + 256, bf);
  hr[tid] = o0;
  hr[tid + 256] = o1;
  hb16[(size_t)t * D_ + tid] = __float2bfloat16(o0);
  hb16[(size_t)t * D_ + tid + 256] = __float2bfloat16(o1);
}

// ---------------- MoE gating: softmax over E=4, top-2, renormalize ----------------
__global__ __launch_bounds__(256) void gate_kernel(const float* __restrict__ hbuf,
                                                   const void* __restrict__ gw, size_t gwoff,
                                                   const void* __restrict__ gb, size_t gboff,
                                                   float* __restrict__ cw,
                                                   const int* __restrict__ flag) {
  const int bf = flag[0];
  int lane = threadIdx.x & 63, wv = threadIdx.x >> 6;
  int t = blockIdx.x * 4 + wv;
  const float* xr = hbuf + (size_t)t * D_;
  float a[4] = {0, 0, 0, 0};
  for (int d = lane; d < D_; d += 64) {
    float xv = xr[d];
#pragma unroll
    for (int e = 0; e < 4; e++) a[e] += xv * ldin(gw, gwoff + e * D_ + d, bf);
  }
#pragma unroll
  for (int e = 0; e < 4; e++)
    for (int off = 32; off; off >>= 1) a[e] += __shfl_xor(a[e], off, 64);
  if (lane == 0) {
    float lg[4];
#pragma unroll
    for (int e = 0; e < 4; e++) lg[e] = a[e] + ldin(gb, gboff + e, bf);
    float m = fmaxf(fmaxf(lg[0], lg[1]), fmaxf(lg[2], lg[3]));
    float p[4], s = 0.f;
#pragma unroll
    for (int e = 0; e < 4; e++) { p[e] = __expf(lg[e] - m); s += p[e]; }
#pragma unroll
    for (int e = 0; e < 4; e++) p[e] /= s;
    int i0 = 0;
    for (int e = 1; e < 4; e++) if (p[e] > p[i0]) i0 = e;   // first occurrence on ties
    int i1 = -1;
    for (int e = 0; e < 4; e++) if (e != i0 && (i1 < 0 || p[e] > p[i1])) i1 = e;
    float s2 = p[i0] + p[i1];
    float outw[4] = {0, 0, 0, 0};
    outw[i0] = p[i0] / s2;
    outw[i1] = p[i1] / s2;
#pragma unroll
    for (int e = 0; e < 4; e++) cw[t * 4 + e] = outw[e];
  }
}

// ---------------- head: out[b,q] = dot(h[b,-1,:], hw[q,:]) + hb[q] ----------------
__global__ __launch_bounds__(256) void head_kernel(const float* __restrict__ hbuf,
                                                   const void* __restrict__ hw,
                                                   const void* __restrict__ hb,
                                                   void* __restrict__ out,
                                                   const int* __restrict__ flag) {
  const int bf = flag[0];
  int bq = blockIdx.x, tid = threadIdx.x;
  int b = bq / 3, q = bq % 3;
  __shared__ float red[256];
  const float* xr = hbuf + (size_t)(b * S_ + (S_ - 1)) * D_;
  float sacc = xr[tid] * ldin(hw, (size_t)q * D_ + tid, bf)
             + xr[tid + 256] * ldin(hw, (size_t)q * D_ + tid + 256, bf);
  red[tid] = sacc; __syncthreads();
  for (int w = 128; w; w >>= 1) { if (tid < w) red[tid] += red[tid + w]; __syncthreads(); }
  if (tid == 0) {
    float r = red[0] + ldin(hb, q, bf);
    if (bf) ((bf16*)out)[bq] = __float2bfloat16(r);
    else    ((float*)out)[bq] = r;
  }
}

extern "C" void kernel_launch(void* const* d_in, const int* in_sizes, int n_in,
                              void* d_out, int out_size, void* d_ws, size_t ws_size,
                              hipStream_t stream) {
  const void* x    = d_in[0];
  const void* Wp   = d_in[1];
  const void* bp   = d_in[2];
  const void* femb = d_in[3];
  const void* qkvw = d_in[4];
  const void* qkvb = d_in[5];
  const void* ow   = d_in[6];
  const void* ob   = d_in[7];
  const void* g1   = d_in[8];
  const void* be1  = d_in[9];
  const void* gw   = d_in[10];
  const void* gb   = d_in[11];
  const void* ew1  = d_in[12];
  const void* eb1  = d_in[13];
  const void* ew2  = d_in[14];
  const void* eb2  = d_in[15];
  const void* g2   = d_in[16];
  const void* be2  = d_in[17];
  const void* hw   = d_in[18];
  const void* hb   = d_in[19];
  const int*  freq = (const int*)d_in[20];

  // workspace layout: ~96 MB peak (Round-2's 101 MB is proven safe)
  int*   flag = (int*)d_ws;
  float* xn   = (float*)d_ws + 64;                  // 65536 f
  float* h    = xn + 65536;                         // T*D f       (16 MB)
  float* qkv  = h + (size_t)T_ * D_;                // T*3D f      (48 MB; hid aliases)
  float* obuf = qkv + (size_t)T_ * D3_;             // T*D f       (16 MB)
  float* cw   = obuf + (size_t)T_ * D_;             // T*4 f
  bf16*  hb16 = (bf16*)(cw + (size_t)T_ * E_);      // T*D bf16    (8 MB)
  bf16*  ao   = hb16 + (size_t)T_ * D_;             // T*D bf16    (8 MB)
  bf16*  hid  = (bf16*)qkv;                         // T*1024 bf16 (16 MB, inside qkv)

  detect_kernel<<<1, 64, 0, stream>>>(x, flag);
  instnorm_kernel<<<B_ * F_, 256, 0, stream>>>(x, xn, flag);
  input_proj_kernel<<<(T_ * D_) / 256, 256, 0, stream>>>(xn, Wp, bp, femb, freq, h, hb16, flag);

  for (int l = 0; l < 3; l++) {
    // QKV projection: [T,512] @ [1536,512]^T -> fp32 qkv
    mfma_gemm<0><<<dim3(D3_ / 128, T_ / 128), 256, 0, stream>>>(
        hb16, qkvw, (size_t)l * D3_ * D_, qkvb, (size_t)l * D3_, qkv,
        D_, D_, D_, D3_, nullptr, nullptr, 0, 0, flag);
    attn_kernel<<<B_ * H_ * (S_ / 64), 256, 0, stream>>>(qkv, ao);
    // output projection: [T,512] @ [512,512]^T -> fp32 obuf
    mfma_gemm<0><<<dim3(D_ / 128, T_ / 128), 256, 0, stream>>>(
        ao, ow, (size_t)l * D_ * D_, ob, (size_t)l * D_, obuf,
        D_, D_, D_, D_, nullptr, nullptr, 0, 0, flag);
    add_ln_kernel<<<T_, 256, 0, stream>>>(h, hb16, obuf, g1, be1, (size_t)l * D_, flag);
    gate_kernel<<<T_ / 4, 256, 0, stream>>>(h, gw, (size_t)l * E_ * D_, gb, (size_t)l * E_, cw, flag);
    // dense per-expert MoE (hid aliases the dead qkv region)
    for (int e = 0; e < E_; e++) {
      // mat1_e: hid = cw[:,e] * relu(hb16 @ ew1[l,e]^T + eb1[l,e])   [T,1024] bf16
      mfma_gemm<1><<<dim3(1024 / 128, T_ / 128), 256, 0, stream>>>(
          hb16, ew1, ((size_t)l * E_ + e) * 1024 * 512, eb1, ((size_t)l * E_ + e) * 1024, hid,
          D_, D_, D_, 1024, cw, nullptr, 0, e, flag);
      // mat2_e: obuf (+)= hid @ ew2[l,e]^T (+ weighted eb2 on e==0)   [T,512] fp32
      mfma_gemm<2><<<dim3(D_ / 128, T_ / 128), 256, 0, stream>>>(
          hid, ew2, ((size_t)l * E_ + e) * 512 * 1024, nullptr, 0, obuf,
          1024, 1024, 1024, D_, cw, eb2, (size_t)l * E_ * D_, e, flag);
    }
    add_ln_kernel<<<T_, 256, 0, stream>>>(h, hb16, obuf, g2, be2, (size_t)l * D_, flag);
  }

  head_kernel<<<24, 256, 0, stream>>>(h, hw, hb, d_out, flag);
}

// Round 5
// 1723.986 us; speedup vs baseline: 11.6036x; 1.3051x over previous
//
#include <hip/hip_runtime.h>
#include <hip/hip_bf16.h>
#include <math.h>

typedef __hip_bfloat16 bf16;
typedef __attribute__((ext_vector_type(8))) short short8;   // 8 bf16 (4 VGPRs)
typedef __attribute__((ext_vector_type(4))) float f32x4;

constexpr int B_ = 8, S_ = 1024, F_ = 8, D_ = 512, H_ = 8, E_ = 4;
constexpr int T_  = B_ * S_;       // 8192 tokens
constexpr int D3_ = 3 * D_;        // 1536

__device__ __forceinline__ float b2f(bf16 v) { return __bfloat162float(v); }
// flag-dispatched input load: bf=1 -> bf16, bf=0 -> fp32 (wave-uniform branch)
__device__ __forceinline__ float ldin(const void* p, size_t i, int bf) {
  return bf ? __bfloat162float(((const bf16*)p)[i]) : ((const float*)p)[i];
}
// async global->LDS, 16 B per lane; lds dest = wave-uniform base + lane*16
__device__ __forceinline__ void gload16(const void* g, void* l) {
  __builtin_amdgcn_global_load_lds((const __attribute__((address_space(1))) unsigned int*)g,
                                   (__attribute__((address_space(3))) unsigned int*)l, 16, 0, 0);
}

// ---------------- dtype detector: writes flag[0]=1 if inputs are bf16 ----------------
__global__ void detect_kernel(const void* __restrict__ x, int* __restrict__ flag) {
  if (threadIdx.x == 0 && blockIdx.x == 0) {
    const unsigned short* u = (const unsigned short*)x;
    int c = 0;
    for (int i = 0; i < 256; i += 2) {
      int ex = (u[i] >> 7) & 0xFF;
      if (ex >= 96 && ex <= 144) c++;
    }
    flag[0] = (c >= 64) ? 1 : 0;
  }
}

// ---------------- instance norm over time axis (ddof=1, eps on std) ----------------
__global__ __launch_bounds__(256) void instnorm_kernel(const void* __restrict__ x,
                                                       float* __restrict__ xn,
                                                       const int* __restrict__ flag) {
  const int bf = flag[0];
  int b = blockIdx.x / F_, f = blockIdx.x % F_;
  int tid = threadIdx.x;
  __shared__ float red[256];
  const int base = b * S_ * F_ + f;
  float s = 0.f;
  for (int j = tid; j < S_; j += 256) s += ldin(x, base + j * F_, bf);
  red[tid] = s; __syncthreads();
  for (int w = 128; w; w >>= 1) { if (tid < w) red[tid] += red[tid + w]; __syncthreads(); }
  float mean = red[0] / S_;
  __syncthreads();
  float v = 0.f;
  for (int j = tid; j < S_; j += 256) { float d = ldin(x, base + j * F_, bf) - mean; v += d * d; }
  red[tid] = v; __syncthreads();
  for (int w = 128; w; w >>= 1) { if (tid < w) red[tid] += red[tid + w]; __syncthreads(); }
  float inv = 1.f / (sqrtf(red[0] / (float)(S_ - 1)) + 1e-5f);
  for (int j = tid; j < S_; j += 256) xn[base + j * F_] = (ldin(x, base + j * F_, bf) - mean) * inv;
}

// ---------------- input projection + freq emb + positional encoding ----------------
__global__ __launch_bounds__(256) void input_proj_kernel(const float* __restrict__ xn,
                                                         const void* __restrict__ Wp,
                                                         const void* __restrict__ bp,
                                                         const void* __restrict__ femb,
                                                         const int* __restrict__ freq_idx,
                                                         float* __restrict__ h,
                                                         bf16* __restrict__ hb16,
                                                         const int* __restrict__ flag) {
  const int bf = flag[0];
  int idx = blockIdx.x * 256 + threadIdx.x;   // < T_*D_
  int d = idx % D_;
  int t = idx / D_;
  int s = t % S_;
  int fi = freq_idx[0];
  float acc = ldin(bp, d, bf) + ldin(femb, (size_t)fi * D_ + d, bf);
  int i2 = d & ~1;
  const float cexp = -9.2103403719761836f / (float)D_;   // -ln(10000)/D
  float ang = (float)s * expf((float)i2 * cexp);
  acc += (d & 1) ? cosf(ang) : sinf(ang);
  const float* xr = xn + t * F_;
#pragma unroll
  for (int f = 0; f < F_; f++) acc += xr[f] * ldin(Wp, (size_t)d * F_ + f, bf);
  h[idx] = acc;
  hb16[idx] = __float2bfloat16(acc);
}

// ---------------- MFMA GEMM: C[m,n] = sum_k A[m,k] * W[n,k] (+epilogue) ----------------
// 128x128 tile, BK=32, 4 waves x (4x4) mfma_f32_16x16x32_bf16. A is bf16 always.
// W is bf16 (flag=1, global_load_lds path) or fp32 (flag=0, convert path).
// MODE 0: C fp32 = acc + bias
// MODE 3: C bf16 = acc + bias                                   (QKV)
// MODE 1: C bf16 = cw[m*4+eidx+(n>>10)] * relu(acc + bias[n])   (MoE mat1, expert pair)
// MODE 2: K=2048 over expert pair; W virtual: e=k>>10.
//         eidx==0: C = acc + sum_e cw*eb2; eidx==1: C += acc    (MoE mat2)
template <int MODE>
__global__ __launch_bounds__(256) void mfma_gemm(
    const bf16* __restrict__ A, const void* __restrict__ Wt, size_t woff,
    const void* __restrict__ bias, size_t boff, void* __restrict__ C_,
    int Kd, int lda, int ldb, int ldc,
    const float* __restrict__ cw, const void* __restrict__ eb2p, size_t e2off,
    int eidx, const int* __restrict__ flag) {
  const int wbf = flag[0];
  __shared__ bf16 As[128][32];
  __shared__ bf16 Bs[128][32];
  const int tid = threadIdx.x;
  const int ln = tid & 63, wv = tid >> 6;
  const int n0 = blockIdx.x * 128;
  const int m0 = blockIdx.y * 128;
  const int wr = (wv >> 1) * 64, wc = (wv & 1) * 64;   // wave quadrant
  const int mrow = ln & 15, quad = ln >> 4;
  const int srow = ln >> 2;          // staging row-in-16 group
  const int skof = (ln & 3) * 8;     // staging k offset (elements)

  f32x4 acc[4][4];
#pragma unroll
  for (int i = 0; i < 4; i++)
#pragma unroll
    for (int j = 0; j < 4; j++) acc[i][j] = (f32x4){0.f, 0.f, 0.f, 0.f};

  for (int k0 = 0; k0 < Kd; k0 += 32) {
    // stage A: 2 x global_load_lds(16B) per thread
#pragma unroll
    for (int j = 0; j < 2; j++) {
      int row = 16 * (4 * j + wv) + srow;
      gload16(A + (size_t)(m0 + row) * lda + k0 + skof,
              (char*)&As[0][0] + (size_t)(4 * j + wv) * 1024);
    }
#pragma unroll
    for (int j = 0; j < 2; j++) {
      int row = 16 * (4 * j + wv) + srow;
      int kk = k0 + skof;
      size_t baddr;
      if (MODE == 2)
        baddr = woff + ((size_t)(kk >> 10) * 512 + (n0 + row)) * 1024 + (kk & 1023);
      else
        baddr = woff + (size_t)(n0 + row) * ldb + kk;
      if (wbf) {
        gload16((const bf16*)Wt + baddr, (char*)&Bs[0][0] + (size_t)(4 * j + wv) * 1024);
      } else {
        const float* g = (const float*)Wt + baddr;
        short8 v;
#pragma unroll
        for (int u = 0; u < 8; u++) {
          bf16 t = __float2bfloat16(g[u]);
          v[u] = *(short*)&t;
        }
        *(short8*)&Bs[row][skof] = v;
      }
    }
    __syncthreads();
    short8 af[4], bfr[4];
#pragma unroll
    for (int t = 0; t < 4; t++) {
      af[t]  = *(const short8*)&As[wr + t * 16 + mrow][quad * 8];
      bfr[t] = *(const short8*)&Bs[wc + t * 16 + mrow][quad * 8];
    }
#pragma unroll
    for (int i = 0; i < 4; i++)
#pragma unroll
      for (int j = 0; j < 4; j++)
        acc[i][j] = __builtin_amdgcn_mfma_f32_16x16x32_bf16(af[i], bfr[j], acc[i][j], 0, 0, 0);
    __syncthreads();
  }

  // epilogue: C/D layout col=lane&15, row=quad*4+reg
#pragma unroll
  for (int tj = 0; tj < 4; tj++) {
    int n = n0 + wc + tj * 16 + mrow;
    float bv = (MODE == 0 || MODE == 1 || MODE == 3) ? ldin(bias, boff + n, wbf) : 0.f;
#pragma unroll
    for (int ti = 0; ti < 4; ti++) {
      int mbase = m0 + wr + ti * 16 + quad * 4;
#pragma unroll
      for (int r = 0; r < 4; r++) {
        int m = mbase + r;
        float v = acc[ti][tj][r];
        if (MODE == 0) {
          ((float*)C_)[(size_t)m * ldc + n] = v + bv;
        } else if (MODE == 3) {
          ((bf16*)C_)[(size_t)m * ldc + n] = __float2bfloat16(v + bv);
        } else if (MODE == 1) {
          ((bf16*)C_)[(size_t)m * ldc + n] =
              __float2bfloat16(fmaxf(v + bv, 0.f) * cw[m * 4 + eidx + (n >> 10)]);
        } else {
          float* cp = (float*)C_ + (size_t)m * ldc + n;
          if (eidx == 0) {
            float badd = 0.f;
#pragma unroll
            for (int e2 = 0; e2 < 4; e2++)
              badd += cw[m * 4 + e2] * ldin(eb2p, e2off + e2 * D_ + n, wbf);
            *cp = v + badd;
          } else {
            *cp += v;
          }
        }
      }
    }
  }
}

// ---------------- MFMA flash attention: one block per (b, h, 64-query tile) ---------
// S = Q K^T and PV via mfma_f32_16x16x32_bf16. Both operands loaded as [row][k8]
// fragments (same convention as mfma_gemm, HW-verified in Round 4). Q/K natural
// row-major; V transposed during staging; P LDS round-trip stays within one wave.
__global__ __launch_bounds__(256) void attn_kernel(const bf16* __restrict__ qkv,
                                                   bf16* __restrict__ o) {
  __shared__ bf16 Qs[64][72];
  __shared__ bf16 Ks[64][72];
  __shared__ bf16 Vt[64][72];   // [d][k]
  __shared__ bf16 Ps[64][72];   // [q][k]
  const int tid = threadIdx.x;
  const int ln = tid & 63, wv = tid >> 6;
  const int mrow = ln & 15, quad = ln >> 4;
  const int qt = blockIdx.x & 15, hh = (blockIdx.x >> 4) & 7, b = blockIdx.x >> 7;
  const int q0 = qt * 64;
  const int sr = tid >> 2;          // staging row 0..63
  const int sc = (tid & 3) * 8;     // staging col (elements); chunks at sc, sc+32

  // stage Q once: Qs[q][d]
  {
    const bf16* src = qkv + (size_t)(b * S_ + q0 + sr) * D3_ + hh * 64;
    *(short8*)&Qs[sr][sc]      = *(const short8*)(src + sc);
    *(short8*)&Qs[sr][sc + 32] = *(const short8*)(src + sc + 32);
  }
  __syncthreads();
  short8 aq[2];
  aq[0] = *(const short8*)&Qs[wv * 16 + mrow][quad * 8];
  aq[1] = *(const short8*)&Qs[wv * 16 + mrow][quad * 8 + 32];

  float m_st[4] = {-1e30f, -1e30f, -1e30f, -1e30f};
  float l_st[4] = {0.f, 0.f, 0.f, 0.f};
  f32x4 oacc[4];
#pragma unroll
  for (int t = 0; t < 4; t++) oacc[t] = (f32x4){0.f, 0.f, 0.f, 0.f};

  for (int kt = 0; kt < 16; kt++) {
    int k0 = kt * 64;
    __syncthreads();   // prev iteration's Vt reads (PV) and Ks reads (S) complete
    // stage K: Ks[k][d]
    {
      const bf16* src = qkv + (size_t)(b * S_ + k0 + sr) * D3_ + D_ + hh * 64;
      *(short8*)&Ks[sr][sc]      = *(const short8*)(src + sc);
      *(short8*)&Ks[sr][sc + 32] = *(const short8*)(src + sc + 32);
    }
    // stage V transposed: Vt[d][k]
    {
      const bf16* src = qkv + (size_t)(b * S_ + k0 + sr) * D3_ + 2 * D_ + hh * 64;
      short8 v0 = *(const short8*)(src + sc);
      short8 v1 = *(const short8*)(src + sc + 32);
#pragma unroll
      for (int u = 0; u < 8; u++) {
        *(short*)&Vt[sc + u][sr]      = v0[u];
        *(short*)&Vt[sc + 32 + u][sr] = v1[u];
      }
    }
    __syncthreads();
    // S tiles: wave's 16 q-rows x 64 keys; D tile rows=q (quad*4+r), cols=key (mrow)
    f32x4 s[4];
#pragma unroll
    for (int t = 0; t < 4; t++) {
      s[t] = (f32x4){0.f, 0.f, 0.f, 0.f};
#pragma unroll
      for (int ks = 0; ks < 2; ks++) {
        short8 bk = *(const short8*)&Ks[t * 16 + mrow][quad * 8 + ks * 32];
        s[t] = __builtin_amdgcn_mfma_f32_16x16x32_bf16(aq[ks], bk, s[t], 0, 0, 0);
      }
    }
    // online softmax per row r (row q = wv*16 + quad*4 + r; 16 lanes share a row)
#pragma unroll
    for (int r = 0; r < 4; r++) {
      float rm = fmaxf(fmaxf(s[0][r], s[1][r]), fmaxf(s[2][r], s[3][r])) * 0.125f;
#pragma unroll
      for (int off = 8; off; off >>= 1) rm = fmaxf(rm, __shfl_xor(rm, off, 64));
      float mnew = fmaxf(m_st[r], rm);
      float alpha = __expf(m_st[r] - mnew);
      m_st[r] = mnew;
      float rs = 0.f;
#pragma unroll
      for (int t = 0; t < 4; t++) {
        float p = __expf(s[t][r] * 0.125f - mnew);
        rs += p;
        Ps[wv * 16 + quad * 4 + r][t * 16 + mrow] = __float2bfloat16(p);
      }
#pragma unroll
      for (int off = 8; off; off >>= 1) rs += __shfl_xor(rs, off, 64);
      l_st[r] = l_st[r] * alpha + rs;
#pragma unroll
      for (int t = 0; t < 4; t++) oacc[t][r] *= alpha;
    }
    // PV: rows of Ps written by this wave are exactly the rows it reads (no barrier)
    short8 ap[2];
    ap[0] = *(const short8*)&Ps[wv * 16 + mrow][quad * 8];
    ap[1] = *(const short8*)&Ps[wv * 16 + mrow][quad * 8 + 32];
#pragma unroll
    for (int t = 0; t < 4; t++) {
#pragma unroll
      for (int ks = 0; ks < 2; ks++) {
        short8 bv = *(const short8*)&Vt[t * 16 + mrow][quad * 8 + ks * 32];
        oacc[t] = __builtin_amdgcn_mfma_f32_16x16x32_bf16(ap[ks], bv, oacc[t], 0, 0, 0);
      }
    }
  }
  // epilogue: O[q][d] = oacc / l ; q = wv*16+quad*4+r, d = t*16+mrow
#pragma unroll
  for (int r = 0; r < 4; r++) {
    float inv = 1.f / l_st[r];
    size_t base = (size_t)(b * S_ + q0 + wv * 16 + quad * 4 + r) * D_ + hh * 64;
#pragma unroll
    for (int t = 0; t < 4; t++)
      o[base + t * 16 + mrow] = __float2bfloat16(oacc[t][r] * inv);
  }
}

// ---------------- residual add + LayerNorm (in-place on h, dual write bf16) ---------
__global__ __launch_bounds__(256) void add_ln_kernel(float* __restrict__ h,
                                                     bf16* __restrict__ hb16,
                                                     const float* __restrict__ o,
                                                     const void* __restrict__ g,
                                                     const void* __restrict__ beta,
                                                     size_t off,
                                                     const int* __restrict__ flag) {
  const int bf = flag[0];
  int t = blockIdx.x, tid = threadIdx.x;
  __shared__ float r1[256], r2[256];
  float* hr = h + (size_t)t * D_;
  const float* orr = o + (size_t)t * D_;
  float v0 = hr[tid] + orr[tid];
  float v1 = hr[tid + 256] + orr[tid + 256];
  r1[tid] = v0 + v1;
  r2[tid] = v0 * v0 + v1 * v1;
  __syncthreads();
  for (int w = 128; w; w >>= 1) { if (tid < w) { r1[tid] += r1[tid + w]; r2[tid] += r2[tid + w]; } __syncthreads(); }
  float mean = r1[0] * (1.f / D_);
  float var  = r2[0] * (1.f / D_) - mean * mean;
  float rstd = rsqrtf(var + 1e-5f);
  float o0 = (v0 - mean) * rstd * ldin(g, off + tid, bf) + ldin(beta, off + tid, bf);
  float o1 = (v1 - mean) * rstd * ldin(g, off + tid + 256, bf) + ldin(beta, off + tid + 256, bf);
  hr[tid] = o0;
  hr[tid + 256] = o1;
  hb16[(size_t)t * D_ + tid] = __float2bfloat16(o0);
  hb16[(size_t)t * D_ + tid + 256] = __float2bfloat16(o1);
}

// ---------------- MoE gating: softmax over E=4, top-2, renormalize ----------------
__global__ __launch_bounds__(256) void gate_kernel(const float* __restrict__ hbuf,
                                                   const void* __restrict__ gw, size_t gwoff,
                                                   const void* __restrict__ gb, size_t gboff,
                                                   float* __restrict__ cw,
                                                   const int* __restrict__ flag) {
  const int bf = flag[0];
  int lane = threadIdx.x & 63, wv = threadIdx.x >> 6;
  int t = blockIdx.x * 4 + wv;
  const float* xr = hbuf + (size_t)t * D_;
  float a[4] = {0, 0, 0, 0};
  for (int d = lane; d < D_; d += 64) {
    float xv = xr[d];
#pragma unroll
    for (int e = 0; e < 4; e++) a[e] += xv * ldin(gw, gwoff + e * D_ + d, bf);
  }
#pragma unroll
  for (int e = 0; e < 4; e++)
    for (int off = 32; off; off >>= 1) a[e] += __shfl_xor(a[e], off, 64);
  if (lane == 0) {
    float lg[4];
#pragma unroll
    for (int e = 0; e < 4; e++) lg[e] = a[e] + ldin(gb, gboff + e, bf);
    float m = fmaxf(fmaxf(lg[0], lg[1]), fmaxf(lg[2], lg[3]));
    float p[4], s = 0.f;
#pragma unroll
    for (int e = 0; e < 4; e++) { p[e] = __expf(lg[e] - m); s += p[e]; }
#pragma unroll
    for (int e = 0; e < 4; e++) p[e] /= s;
    int i0 = 0;
    for (int e = 1; e < 4; e++) if (p[e] > p[i0]) i0 = e;   // first occurrence on ties
    int i1 = -1;
    for (int e = 0; e < 4; e++) if (e != i0 && (i1 < 0 || p[e] > p[i1])) i1 = e;
    float s2 = p[i0] + p[i1];
    float outw[4] = {0, 0, 0, 0};
    outw[i0] = p[i0] / s2;
    outw[i1] = p[i1] / s2;
#pragma unroll
    for (int e = 0; e < 4; e++) cw[t * 4 + e] = outw[e];
  }
}

// ---------------- head: out[b,q] = dot(h[b,-1,:], hw[q,:]) + hb[q] ----------------
__global__ __launch_bounds__(256) void head_kernel(const float* __restrict__ hbuf,
                                                   const void* __restrict__ hw,
                                                   const void* __restrict__ hb,
                                                   void* __restrict__ out,
                                                   const int* __restrict__ flag) {
  const int bf = flag[0];
  int bq = blockIdx.x, tid = threadIdx.x;
  int b = bq / 3, q = bq % 3;
  __shared__ float red[256];
  const float* xr = hbuf + (size_t)(b * S_ + (S_ - 1)) * D_;
  float sacc = xr[tid] * ldin(hw, (size_t)q * D_ + tid, bf)
             + xr[tid + 256] * ldin(hw, (size_t)q * D_ + tid + 256, bf);
  red[tid] = sacc; __syncthreads();
  for (int w = 128; w; w >>= 1) { if (tid < w) red[tid] += red[tid + w]; __syncthreads(); }
  if (tid == 0) {
    float r = red[0] + ldin(hb, q, bf);
    if (bf) ((bf16*)out)[bq] = __float2bfloat16(r);
    else    ((float*)out)[bq] = r;
  }
}

extern "C" void kernel_launch(void* const* d_in, const int* in_sizes, int n_in,
                              void* d_out, int out_size, void* d_ws, size_t ws_size,
                              hipStream_t stream) {
  const void* x    = d_in[0];
  const void* Wp   = d_in[1];
  const void* bp   = d_in[2];
  const void* femb = d_in[3];
  const void* qkvw = d_in[4];
  const void* qkvb = d_in[5];
  const void* ow   = d_in[6];
  const void* ob   = d_in[7];
  const void* g1   = d_in[8];
  const void* be1  = d_in[9];
  const void* gw   = d_in[10];
  const void* gb   = d_in[11];
  const void* ew1  = d_in[12];
  const void* eb1  = d_in[13];
  const void* ew2  = d_in[14];
  const void* eb2  = d_in[15];
  const void* g2   = d_in[16];
  const void* be2  = d_in[17];
  const void* hw   = d_in[18];
  const void* hb   = d_in[19];
  const int*  freq = (const int*)d_in[20];

  // workspace layout: ~76 MB peak (proven-safe bound: 101 MB)
  int*   flag = (int*)d_ws;
  float* xn   = (float*)d_ws + 64;                  // 65536 f
  float* h    = xn + 65536;                         // T*D f       (16 MB)
  float* obuf = h + (size_t)T_ * D_;                // T*D f       (16 MB)
  float* cw   = obuf + (size_t)T_ * D_;             // T*4 f
  bf16*  hb16 = (bf16*)(cw + (size_t)T_ * E_);      // T*D bf16    (8 MB)
  bf16*  qkvb16 = hb16 + (size_t)T_ * D_;           // T*3D bf16   (24 MB)
  bf16*  ao   = qkvb16 + (size_t)T_ * D3_;          // T*D bf16    (8 MB)
  bf16*  hid  = qkvb16;                             // T*2048 bf16 (32 MB = qkv+ao exactly)

  detect_kernel<<<1, 64, 0, stream>>>(x, flag);
  instnorm_kernel<<<B_ * F_, 256, 0, stream>>>(x, xn, flag);
  input_proj_kernel<<<(T_ * D_) / 256, 256, 0, stream>>>(xn, Wp, bp, femb, freq, h, hb16, flag);

  for (int l = 0; l < 3; l++) {
    // QKV projection -> bf16 qkv
    mfma_gemm<3><<<dim3(D3_ / 128, T_ / 128), 256, 0, stream>>>(
        hb16, qkvw, (size_t)l * D3_ * D_, qkvb, (size_t)l * D3_, qkvb16,
        D_, D_, D_, D3_, nullptr, nullptr, 0, 0, flag);
    attn_kernel<<<B_ * H_ * (S_ / 64), 256, 0, stream>>>(qkvb16, ao);
    // output projection -> fp32 obuf
    mfma_gemm<0><<<dim3(D_ / 128, T_ / 128), 256, 0, stream>>>(
        ao, ow, (size_t)l * D_ * D_, ob, (size_t)l * D_, obuf,
        D_, D_, D_, D_, nullptr, nullptr, 0, 0, flag);
    add_ln_kernel<<<T_, 256, 0, stream>>>(h, hb16, obuf, g1, be1, (size_t)l * D_, flag);
    gate_kernel<<<T_ / 4, 256, 0, stream>>>(h, gw, (size_t)l * E_ * D_, gb, (size_t)l * E_, cw, flag);
    // MoE as two expert-pair super-GEMMs (hid aliases qkv+ao, both dead here)
    for (int pair = 0; pair < 2; pair++) {
      // mat1: hid[T,2048] = cw * relu(hb16 @ ew1[l, 2p:2p+2]^T + eb1)
      mfma_gemm<1><<<dim3(2048 / 128, T_ / 128), 256, 0, stream>>>(
          hb16, ew1, ((size_t)l * 4 + pair * 2) * 1024 * 512, eb1,
          (size_t)l * 4096 + pair * 2048, hid,
          D_, D_, D_, 2048, cw, nullptr, 0, pair * 2, flag);
      // mat2: obuf (+)= hid @ W2pair^T (K=2048 virtual); pair 0 adds weighted eb2
      mfma_gemm<2><<<dim3(D_ / 128, T_ / 128), 256, 0, stream>>>(
          hid, ew2, ((size_t)l * 4 + pair * 2) * 512 * 1024, nullptr, 0, obuf,
          2048, 2048, 0, D_, cw, eb2, (size_t)l * 4 * D_, pair, flag);
    }
    add_ln_kernel<<<T_, 256, 0, stream>>>(h, hb16, obuf, g2, be2, (size_t)l * D_, flag);
  }

  head_kernel<<<24, 256, 0, stream>>>(h, hw, hb, d_out, flag);
}

// Round 6
// 1564.724 us; speedup vs baseline: 12.7847x; 1.1018x over previous
//
#include <hip/hip_runtime.h>
#include <hip/hip_bf16.h>
#include <math.h>

typedef __hip_bfloat16 bf16;
typedef __attribute__((ext_vector_type(8))) short short8;   // 8 bf16 (4 VGPRs)
typedef __attribute__((ext_vector_type(4))) float f32x4;

constexpr int B_ = 8, S_ = 1024, F_ = 8, D_ = 512, H_ = 8, E_ = 4;
constexpr int T_  = B_ * S_;       // 8192 tokens
constexpr int D3_ = 3 * D_;        // 1536

__device__ __forceinline__ float b2f(bf16 v) { return __bfloat162float(v); }
// flag-dispatched input load: bf=1 -> bf16, bf=0 -> fp32 (wave-uniform branch)
__device__ __forceinline__ float ldin(const void* p, size_t i, int bf) {
  return bf ? __bfloat162float(((const bf16*)p)[i]) : ((const float*)p)[i];
}
// async global->LDS, 16 B per lane; lds dest = wave-uniform base + lane*16
__device__ __forceinline__ void gload16(const void* g, void* l) {
  __builtin_amdgcn_global_load_lds((const __attribute__((address_space(1))) unsigned int*)g,
                                   (__attribute__((address_space(3))) unsigned int*)l, 16, 0, 0);
}

// ---------------- dtype detector: writes flag[0]=1 if inputs are bf16 ----------------
__global__ void detect_kernel(const void* __restrict__ x, int* __restrict__ flag) {
  if (threadIdx.x == 0 && blockIdx.x == 0) {
    const unsigned short* u = (const unsigned short*)x;
    int c = 0;
    for (int i = 0; i < 256; i += 2) {
      int ex = (u[i] >> 7) & 0xFF;
      if (ex >= 96 && ex <= 144) c++;
    }
    flag[0] = (c >= 64) ? 1 : 0;
  }
}

// ---------------- instance norm over time axis (ddof=1, eps on std) ----------------
__global__ __launch_bounds__(256) void instnorm_kernel(const void* __restrict__ x,
                                                       float* __restrict__ xn,
                                                       const int* __restrict__ flag) {
  const int bf = flag[0];
  int b = blockIdx.x / F_, f = blockIdx.x % F_;
  int tid = threadIdx.x;
  __shared__ float red[256];
  const int base = b * S_ * F_ + f;
  float s = 0.f;
  for (int j = tid; j < S_; j += 256) s += ldin(x, base + j * F_, bf);
  red[tid] = s; __syncthreads();
  for (int w = 128; w; w >>= 1) { if (tid < w) red[tid] += red[tid + w]; __syncthreads(); }
  float mean = red[0] / S_;
  __syncthreads();
  float v = 0.f;
  for (int j = tid; j < S_; j += 256) { float d = ldin(x, base + j * F_, bf) - mean; v += d * d; }
  red[tid] = v; __syncthreads();
  for (int w = 128; w; w >>= 1) { if (tid < w) red[tid] += red[tid + w]; __syncthreads(); }
  float inv = 1.f / (sqrtf(red[0] / (float)(S_ - 1)) + 1e-5f);
  for (int j = tid; j < S_; j += 256) xn[base + j * F_] = (ldin(x, base + j * F_, bf) - mean) * inv;
}

// ---------------- input projection + freq emb + positional encoding ----------------
__global__ __launch_bounds__(256) void input_proj_kernel(const float* __restrict__ xn,
                                                         const void* __restrict__ Wp,
                                                         const void* __restrict__ bp,
                                                         const void* __restrict__ femb,
                                                         const int* __restrict__ freq_idx,
                                                         float* __restrict__ h,
                                                         bf16* __restrict__ hb16,
                                                         const int* __restrict__ flag) {
  const int bf = flag[0];
  int idx = blockIdx.x * 256 + threadIdx.x;   // < T_*D_
  int d = idx % D_;
  int t = idx / D_;
  int s = t % S_;
  int fi = freq_idx[0];
  float acc = ldin(bp, d, bf) + ldin(femb, (size_t)fi * D_ + d, bf);
  int i2 = d & ~1;
  const float cexp = -9.2103403719761836f / (float)D_;   // -ln(10000)/D
  float ang = (float)s * expf((float)i2 * cexp);
  acc += (d & 1) ? cosf(ang) : sinf(ang);
  const float* xr = xn + t * F_;
#pragma unroll
  for (int f = 0; f < F_; f++) acc += xr[f] * ldin(Wp, (size_t)d * F_ + f, bf);
  h[idx] = acc;
  hb16[idx] = __float2bfloat16(acc);
}

// ---------------- obuf init: mode 0 -> bias broadcast; mode 1 -> sum_e cw*eb2 -------
__global__ __launch_bounds__(256) void obuf_init_kernel(float* __restrict__ obuf,
                                                        const void* __restrict__ bias,
                                                        size_t boff,
                                                        const float* __restrict__ cw,
                                                        const void* __restrict__ eb2p,
                                                        size_t e2off, int mode,
                                                        const int* __restrict__ flag) {
  const int bf = flag[0];
  int idx = blockIdx.x * 256 + threadIdx.x;   // < T_*D_
  int n = idx % D_, t = idx / D_;
  if (mode == 0) {
    obuf[idx] = ldin(bias, boff + n, bf);
  } else {
    float v = 0.f;
#pragma unroll
    for (int e = 0; e < 4; e++) v += cw[t * 4 + e] * ldin(eb2p, e2off + e * D_ + n, bf);
    obuf[idx] = v;
  }
}

// ---------------- MFMA GEMM: C[m,n] = sum_k A[m,k] * W[n,k] (+epilogue) ----------------
// 128x128 tile, BK=32, 4 waves x (4x4) mfma_f32_16x16x32_bf16. A is bf16 always.
// W is bf16 (flag=1, global_load_lds path) or fp32 (flag=0, convert path).
// Split-K via gridDim.z: each z-block does Kd/gridDim.z and (MODE 0/2) atomicAdds.
// MODE 0: C fp32 atomicAdd acc                 (obuf pre-inited with bias)
// MODE 3: C bf16 = acc + bias                  (QKV)
// MODE 1: C bf16 = cw[m*4+eidx+(n>>10)] * relu(acc + bias[n])   (MoE mat1, expert pair)
// MODE 2: W virtual: e=k>>10; C fp32 atomicAdd (obuf pre-inited with weighted eb2)
template <int MODE>
__global__ __launch_bounds__(256) void mfma_gemm(
    const bf16* __restrict__ A, const void* __restrict__ Wt, size_t woff,
    const void* __restrict__ bias, size_t boff, void* __restrict__ C_,
    int Kd, int lda, int ldb, int ldc,
    const float* __restrict__ cw, int eidx, const int* __restrict__ flag) {
  const int wbf = flag[0];
  __shared__ bf16 As[128][32];
  __shared__ bf16 Bs[128][32];
  const int tid = threadIdx.x;
  const int ln = tid & 63, wv = tid >> 6;
  const int n0 = blockIdx.x * 128;
  const int m0 = blockIdx.y * 128;
  const int wr = (wv >> 1) * 64, wc = (wv & 1) * 64;   // wave quadrant
  const int mrow = ln & 15, quad = ln >> 4;
  const int srow = ln >> 2;          // staging row-in-16 group
  const int skof = (ln & 3) * 8;     // staging k offset (elements)
  const int kchunk = Kd / gridDim.z;
  const int kbeg = blockIdx.z * kchunk;

  f32x4 acc[4][4];
#pragma unroll
  for (int i = 0; i < 4; i++)
#pragma unroll
    for (int j = 0; j < 4; j++) acc[i][j] = (f32x4){0.f, 0.f, 0.f, 0.f};

  for (int k0 = kbeg; k0 < kbeg + kchunk; k0 += 32) {
    // stage A: 2 x global_load_lds(16B) per thread
#pragma unroll
    for (int j = 0; j < 2; j++) {
      int row = 16 * (4 * j + wv) + srow;
      gload16(A + (size_t)(m0 + row) * lda + k0 + skof,
              (char*)&As[0][0] + (size_t)(4 * j + wv) * 1024);
    }
#pragma unroll
    for (int j = 0; j < 2; j++) {
      int row = 16 * (4 * j + wv) + srow;
      int kk = k0 + skof;
      size_t baddr;
      if (MODE == 2)
        baddr = woff + ((size_t)(kk >> 10) * 512 + (n0 + row)) * 1024 + (kk & 1023);
      else
        baddr = woff + (size_t)(n0 + row) * ldb + kk;
      if (wbf) {
        gload16((const bf16*)Wt + baddr, (char*)&Bs[0][0] + (size_t)(4 * j + wv) * 1024);
      } else {
        const float* g = (const float*)Wt + baddr;
        short8 v;
#pragma unroll
        for (int u = 0; u < 8; u++) {
          bf16 t = __float2bfloat16(g[u]);
          v[u] = *(short*)&t;
        }
        *(short8*)&Bs[row][skof] = v;
      }
    }
    __syncthreads();
    short8 af[4], bfr[4];
#pragma unroll
    for (int t = 0; t < 4; t++) {
      af[t]  = *(const short8*)&As[wr + t * 16 + mrow][quad * 8];
      bfr[t] = *(const short8*)&Bs[wc + t * 16 + mrow][quad * 8];
    }
#pragma unroll
    for (int i = 0; i < 4; i++)
#pragma unroll
      for (int j = 0; j < 4; j++)
        acc[i][j] = __builtin_amdgcn_mfma_f32_16x16x32_bf16(af[i], bfr[j], acc[i][j], 0, 0, 0);
    __syncthreads();
  }

  // epilogue: C/D layout col=lane&15, row=quad*4+reg
#pragma unroll
  for (int tj = 0; tj < 4; tj++) {
    int n = n0 + wc + tj * 16 + mrow;
    float bv = (MODE == 1 || MODE == 3) ? ldin(bias, boff + n, wbf) : 0.f;
#pragma unroll
    for (int ti = 0; ti < 4; ti++) {
      int mbase = m0 + wr + ti * 16 + quad * 4;
#pragma unroll
      for (int r = 0; r < 4; r++) {
        int m = mbase + r;
        float v = acc[ti][tj][r];
        if (MODE == 0 || MODE == 2) {
          atomicAdd((float*)C_ + (size_t)m * ldc + n, v);
        } else if (MODE == 3) {
          ((bf16*)C_)[(size_t)m * ldc + n] = __float2bfloat16(v + bv);
        } else {   // MODE 1
          ((bf16*)C_)[(size_t)m * ldc + n] =
              __float2bfloat16(fmaxf(v + bv, 0.f) * cw[m * 4 + eidx + (n >> 10)]);
        }
      }
    }
  }
}

// ---------------- MFMA flash attention: one block per (b, h, 64-query tile) ---------
__global__ __launch_bounds__(256) void attn_kernel(const bf16* __restrict__ qkv,
                                                   bf16* __restrict__ o) {
  __shared__ bf16 Qs[64][72];
  __shared__ bf16 Ks[64][72];
  __shared__ bf16 Vt[64][72];   // [d][k]
  __shared__ bf16 Ps[64][72];   // [q][k]
  const int tid = threadIdx.x;
  const int ln = tid & 63, wv = tid >> 6;
  const int mrow = ln & 15, quad = ln >> 4;
  const int qt = blockIdx.x & 15, hh = (blockIdx.x >> 4) & 7, b = blockIdx.x >> 7;
  const int q0 = qt * 64;
  const int sr = tid >> 2;          // staging row 0..63
  const int sc = (tid & 3) * 8;     // staging col (elements); chunks at sc, sc+32

  // stage Q once: Qs[q][d]
  {
    const bf16* src = qkv + (size_t)(b * S_ + q0 + sr) * D3_ + hh * 64;
    *(short8*)&Qs[sr][sc]      = *(const short8*)(src + sc);
    *(short8*)&Qs[sr][sc + 32] = *(const short8*)(src + sc + 32);
  }
  __syncthreads();
  short8 aq[2];
  aq[0] = *(const short8*)&Qs[wv * 16 + mrow][quad * 8];
  aq[1] = *(const short8*)&Qs[wv * 16 + mrow][quad * 8 + 32];

  float m_st[4] = {-1e30f, -1e30f, -1e30f, -1e30f};
  float l_st[4] = {0.f, 0.f, 0.f, 0.f};
  f32x4 oacc[4];
#pragma unroll
  for (int t = 0; t < 4; t++) oacc[t] = (f32x4){0.f, 0.f, 0.f, 0.f};

  for (int kt = 0; kt < 16; kt++) {
    int k0 = kt * 64;
    __syncthreads();   // prev iteration's Vt reads (PV) and Ks reads (S) complete
    // stage K: Ks[k][d]
    {
      const bf16* src = qkv + (size_t)(b * S_ + k0 + sr) * D3_ + D_ + hh * 64;
      *(short8*)&Ks[sr][sc]      = *(const short8*)(src + sc);
      *(short8*)&Ks[sr][sc + 32] = *(const short8*)(src + sc + 32);
    }
    // stage V transposed: Vt[d][k]
    {
      const bf16* src = qkv + (size_t)(b * S_ + k0 + sr) * D3_ + 2 * D_ + hh * 64;
      short8 v0 = *(const short8*)(src + sc);
      short8 v1 = *(const short8*)(src + sc + 32);
#pragma unroll
      for (int u = 0; u < 8; u++) {
        *(short*)&Vt[sc + u][sr]      = v0[u];
        *(short*)&Vt[sc + 32 + u][sr] = v1[u];
      }
    }
    __syncthreads();
    // S tiles: wave's 16 q-rows x 64 keys
    f32x4 s[4];
#pragma unroll
    for (int t = 0; t < 4; t++) {
      s[t] = (f32x4){0.f, 0.f, 0.f, 0.f};
#pragma unroll
      for (int ks = 0; ks < 2; ks++) {
        short8 bk = *(const short8*)&Ks[t * 16 + mrow][quad * 8 + ks * 32];
        s[t] = __builtin_amdgcn_mfma_f32_16x16x32_bf16(aq[ks], bk, s[t], 0, 0, 0);
      }
    }
    // online softmax per row r (row q = wv*16 + quad*4 + r; 16 lanes share a row)
#pragma unroll
    for (int r = 0; r < 4; r++) {
      float rm = fmaxf(fmaxf(s[0][r], s[1][r]), fmaxf(s[2][r], s[3][r])) * 0.125f;
#pragma unroll
      for (int off = 8; off; off >>= 1) rm = fmaxf(rm, __shfl_xor(rm, off, 64));
      float mnew = fmaxf(m_st[r], rm);
      float alpha = __expf(m_st[r] - mnew);
      m_st[r] = mnew;
      float rs = 0.f;
#pragma unroll
      for (int t = 0; t < 4; t++) {
        float p = __expf(s[t][r] * 0.125f - mnew);
        rs += p;
        Ps[wv * 16 + quad * 4 + r][t * 16 + mrow] = __float2bfloat16(p);
      }
#pragma unroll
      for (int off = 8; off; off >>= 1) rs += __shfl_xor(rs, off, 64);
      l_st[r] = l_st[r] * alpha + rs;
#pragma unroll
      for (int t = 0; t < 4; t++) oacc[t][r] *= alpha;
    }
    // PV: rows of Ps written by this wave are exactly the rows it reads (no barrier)
    short8 ap[2];
    ap[0] = *(const short8*)&Ps[wv * 16 + mrow][quad * 8];
    ap[1] = *(const short8*)&Ps[wv * 16 + mrow][quad * 8 + 32];
#pragma unroll
    for (int t = 0; t < 4; t++) {
#pragma unroll
      for (int ks = 0; ks < 2; ks++) {
        short8 bv = *(const short8*)&Vt[t * 16 + mrow][quad * 8 + ks * 32];
        oacc[t] = __builtin_amdgcn_mfma_f32_16x16x32_bf16(ap[ks], bv, oacc[t], 0, 0, 0);
      }
    }
  }
  // epilogue: O[q][d] = oacc / l ; q = wv*16+quad*4+r, d = t*16+mrow
#pragma unroll
  for (int r = 0; r < 4; r++) {
    float inv = 1.f / l_st[r];
    size_t base = (size_t)(b * S_ + q0 + wv * 16 + quad * 4 + r) * D_ + hh * 64;
#pragma unroll
    for (int t = 0; t < 4; t++)
      o[base + t * 16 + mrow] = __float2bfloat16(oacc[t][r] * inv);
  }
}

// ---------------- residual add + LayerNorm (in-place on h, dual write bf16) ---------
__global__ __launch_bounds__(256) void add_ln_kernel(float* __restrict__ h,
                                                     bf16* __restrict__ hb16,
                                                     const float* __restrict__ o,
                                                     const void* __restrict__ g,
                                                     const void* __restrict__ beta,
                                                     size_t off,
                                                     const int* __restrict__ flag) {
  const int bf = flag[0];
  int t = blockIdx.x, tid = threadIdx.x;
  __shared__ float r1[256], r2[256];
  float* hr = h + (size_t)t * D_;
  const float* orr = o + (size_t)t * D_;
  float v0 = hr[tid] + orr[tid];
  float v1 = hr[tid + 256] + orr[tid + 256];
  r1[tid] = v0 + v1;
  r2[tid] = v0 * v0 + v1 * v1;
  __syncthreads();
  for (int w = 128; w; w >>= 1) { if (tid < w) { r1[tid] += r1[tid + w]; r2[tid] += r2[tid + w]; } __syncthreads(); }
  float mean = r1[0] * (1.f / D_);
  float var  = r2[0] * (1.f / D_) - mean * mean;
  float rstd = rsqrtf(var + 1e-5f);
  float o0 = (v0 - mean) * rstd * ldin(g, off + tid, bf) + ldin(beta, off + tid, bf);
  float o1 = (v1 - mean) * rstd * ldin(g, off + tid + 256, bf) + ldin(beta, off + tid + 256, bf);
  hr[tid] = o0;
  hr[tid + 256] = o1;
  hb16[(size_t)t * D_ + tid] = __float2bfloat16(o0);
  hb16[(size_t)t * D_ + tid + 256] = __float2bfloat16(o1);
}

// ---------------- MoE gating: softmax over E=4, top-2, renormalize ----------------
__global__ __launch_bounds__(256) void gate_kernel(const float* __restrict__ hbuf,
                                                   const void* __restrict__ gw, size_t gwoff,
                                                   const void* __restrict__ gb, size_t gboff,
                                                   float* __restrict__ cw,
                                                   const int* __restrict__ flag) {
  const int bf = flag[0];
  int lane = threadIdx.x & 63, wv = threadIdx.x >> 6;
  int t = blockIdx.x * 4 + wv;
  const float* xr = hbuf + (size_t)t * D_;
  float a[4] = {0, 0, 0, 0};
  for (int d = lane; d < D_; d += 64) {
    float xv = xr[d];
#pragma unroll
    for (int e = 0; e < 4; e++) a[e] += xv * ldin(gw, gwoff + e * D_ + d, bf);
  }
#pragma unroll
  for (int e = 0; e < 4; e++)
    for (int off = 32; off; off >>= 1) a[e] += __shfl_xor(a[e], off, 64);
  if (lane == 0) {
    float lg[4];
#pragma unroll
    for (int e = 0; e < 4; e++) lg[e] = a[e] + ldin(gb, gboff + e, bf);
    float m = fmaxf(fmaxf(lg[0], lg[1]), fmaxf(lg[2], lg[3]));
    float p[4], s = 0.f;
#pragma unroll
    for (int e = 0; e < 4; e++) { p[e] = __expf(lg[e] - m); s += p[e]; }
#pragma unroll
    for (int e = 0; e < 4; e++) p[e] /= s;
    int i0 = 0;
    for (int e = 1; e < 4; e++) if (p[e] > p[i0]) i0 = e;   // first occurrence on ties
    int i1 = -1;
    for (int e = 0; e < 4; e++) if (e != i0 && (i1 < 0 || p[e] > p[i1])) i1 = e;
    float s2 = p[i0] + p[i1];
    float outw[4] = {0, 0, 0, 0};
    outw[i0] = p[i0] / s2;
    outw[i1] = p[i1] / s2;
#pragma unroll
    for (int e = 0; e < 4; e++) cw[t * 4 + e] = outw[e];
  }
}

// ---------------- head: out[b,q] = dot(h[b,-1,:], hw[q,:]) + hb[q] ----------------
__global__ __launch_bounds__(256) void head_kernel(const float* __restrict__ hbuf,
                                                   const void* __restrict__ hw,
                                                   const void* __restrict__ hb,
                                                   void* __restrict__ out,
                                                   const int* __restrict__ flag) {
  const int bf = flag[0];
  int bq = blockIdx.x, tid = threadIdx.x;
  int b = bq / 3, q = bq % 3;
  __shared__ float red[256];
  const float* xr = hbuf + (size_t)(b * S_ + (S_ - 1)) * D_;
  float sacc = xr[tid] * ldin(hw, (size_t)q * D_ + tid, bf)
             + xr[tid + 256] * ldin(hw, (size_t)q * D_ + tid + 256, bf);
  red[tid] = sacc; __syncthreads();
  for (int w = 128; w; w >>= 1) { if (tid < w) red[tid] += red[tid + w]; __syncthreads(); }
  if (tid == 0) {
    float r = red[0] + ldin(hb, q, bf);
    if (bf) ((bf16*)out)[bq] = __float2bfloat16(r);
    else    ((float*)out)[bq] = r;
  }
}

extern "C" void kernel_launch(void* const* d_in, const int* in_sizes, int n_in,
                              void* d_out, int out_size, void* d_ws, size_t ws_size,
                              hipStream_t stream) {
  const void* x    = d_in[0];
  const void* Wp   = d_in[1];
  const void* bp   = d_in[2];
  const void* femb = d_in[3];
  const void* qkvw = d_in[4];
  const void* qkvb = d_in[5];
  const void* ow   = d_in[6];
  const void* ob   = d_in[7];
  const void* g1   = d_in[8];
  const void* be1  = d_in[9];
  const void* gw   = d_in[10];
  const void* gb   = d_in[11];
  const void* ew1  = d_in[12];
  const void* eb1  = d_in[13];
  const void* ew2  = d_in[14];
  const void* eb2  = d_in[15];
  const void* g2   = d_in[16];
  const void* be2  = d_in[17];
  const void* hw   = d_in[18];
  const void* hb   = d_in[19];
  const int*  freq = (const int*)d_in[20];

  // workspace layout: ~76 MB peak (proven-safe bound: 101 MB)
  int*   flag = (int*)d_ws;
  float* xn   = (float*)d_ws + 64;                  // 65536 f
  float* h    = xn + 65536;                         // T*D f       (16 MB)
  float* obuf = h + (size_t)T_ * D_;                // T*D f       (16 MB)
  float* cw   = obuf + (size_t)T_ * D_;             // T*4 f
  bf16*  hb16 = (bf16*)(cw + (size_t)T_ * E_);      // T*D bf16    (8 MB)
  bf16*  qkvb16 = hb16 + (size_t)T_ * D_;           // T*3D bf16   (24 MB)
  bf16*  ao   = qkvb16 + (size_t)T_ * D3_;          // T*D bf16    (8 MB)
  bf16*  hid  = qkvb16;                             // T*2048 bf16 (32 MB = qkv+ao exactly)

  detect_kernel<<<1, 64, 0, stream>>>(x, flag);
  instnorm_kernel<<<B_ * F_, 256, 0, stream>>>(x, xn, flag);
  input_proj_kernel<<<(T_ * D_) / 256, 256, 0, stream>>>(xn, Wp, bp, femb, freq, h, hb16, flag);

  for (int l = 0; l < 3; l++) {
    // QKV projection -> bf16 qkv
    mfma_gemm<3><<<dim3(D3_ / 128, T_ / 128), 256, 0, stream>>>(
        hb16, qkvw, (size_t)l * D3_ * D_, qkvb, (size_t)l * D3_, qkvb16,
        D_, D_, D_, D3_, nullptr, 0, flag);
    attn_kernel<<<B_ * H_ * (S_ / 64), 256, 0, stream>>>(qkvb16, ao);
    // O-projection: obuf = ob (init) then split-K=2 atomic GEMM
    obuf_init_kernel<<<(T_ * D_) / 256, 256, 0, stream>>>(
        obuf, ob, (size_t)l * D_, nullptr, nullptr, 0, 0, flag);
    mfma_gemm<0><<<dim3(D_ / 128, T_ / 128, 2), 256, 0, stream>>>(
        ao, ow, (size_t)l * D_ * D_, nullptr, 0, obuf,
        D_, D_, D_, D_, nullptr, 0, flag);
    add_ln_kernel<<<T_, 256, 0, stream>>>(h, hb16, obuf, g1, be1, (size_t)l * D_, flag);
    gate_kernel<<<T_ / 4, 256, 0, stream>>>(h, gw, (size_t)l * E_ * D_, gb, (size_t)l * E_, cw, flag);
    // MoE: obuf = sum_e cw*eb2 (init), then per expert-pair mat1 + split-K=4 mat2
    obuf_init_kernel<<<(T_ * D_) / 256, 256, 0, stream>>>(
        obuf, nullptr, 0, cw, eb2, (size_t)l * 4 * D_, 1, flag);
    for (int pair = 0; pair < 2; pair++) {
      // mat1: hid[T,2048] = cw * relu(hb16 @ ew1[l, 2p:2p+2]^T + eb1)
      mfma_gemm<1><<<dim3(2048 / 128, T_ / 128), 256, 0, stream>>>(
          hb16, ew1, ((size_t)l * 4 + pair * 2) * 1024 * 512, eb1,
          (size_t)l * 4096 + pair * 2048, hid,
          D_, D_, D_, 2048, cw, pair * 2, flag);
      // mat2: obuf += hid @ W2pair^T (K=2048 virtual, split-K=4, atomic)
      mfma_gemm<2><<<dim3(D_ / 128, T_ / 128, 4), 256, 0, stream>>>(
          hid, ew2, ((size_t)l * 4 + pair * 2) * 512 * 1024, nullptr, 0, obuf,
          2048, 2048, 0, D_, nullptr, pair, flag);
    }
    add_ln_kernel<<<T_, 256, 0, stream>>>(h, hb16, obuf, g2, be2, (size_t)l * D_, flag);
  }

  head_kernel<<<24, 256, 0, stream>>>(h, hw, hb, d_out, flag);
}

// Round 7
// 1382.492 us; speedup vs baseline: 14.4699x; 1.1318x over previous
//
#include <hip/hip_runtime.h>
#include <hip/hip_bf16.h>
#include <math.h>

typedef __hip_bfloat16 bf16;
typedef __attribute__((ext_vector_type(8))) short short8;   // 8 bf16 (4 VGPRs)
typedef __attribute__((ext_vector_type(4))) float f32x4;

constexpr int B_ = 8, S_ = 1024, F_ = 8, D_ = 512, H_ = 8, E_ = 4;
constexpr int T_  = B_ * S_;       // 8192 tokens
constexpr int D3_ = 3 * D_;        // 1536

__device__ __forceinline__ float b2f(bf16 v) { return __bfloat162float(v); }
// flag-dispatched input load: bf=1 -> bf16, bf=0 -> fp32 (wave-uniform branch)
__device__ __forceinline__ float ldin(const void* p, size_t i, int bf) {
  return bf ? __bfloat162float(((const bf16*)p)[i]) : ((const float*)p)[i];
}
// async global->LDS, 16 B per lane; lds dest = wave-uniform base + lane*16
__device__ __forceinline__ void gload16(const void* g, void* l) {
  __builtin_amdgcn_global_load_lds((const __attribute__((address_space(1))) unsigned int*)g,
                                   (__attribute__((address_space(3))) unsigned int*)l, 16, 0, 0);
}

// ---------------- dtype detector: writes flag[0]=1 if inputs are bf16 ----------------
__global__ void detect_kernel(const void* __restrict__ x, int* __restrict__ flag) {
  if (threadIdx.x == 0 && blockIdx.x == 0) {
    const unsigned short* u = (const unsigned short*)x;
    int c = 0;
    for (int i = 0; i < 256; i += 2) {
      int ex = (u[i] >> 7) & 0xFF;
      if (ex >= 96 && ex <= 144) c++;
    }
    flag[0] = (c >= 64) ? 1 : 0;
  }
}

// ---------------- instance norm over time axis (ddof=1, eps on std) ----------------
__global__ __launch_bounds__(256) void instnorm_kernel(const void* __restrict__ x,
                                                       float* __restrict__ xn,
                                                       const int* __restrict__ flag) {
  const int bf = flag[0];
  int b = blockIdx.x / F_, f = blockIdx.x % F_;
  int tid = threadIdx.x;
  __shared__ float red[256];
  const int base = b * S_ * F_ + f;
  float s = 0.f;
  for (int j = tid; j < S_; j += 256) s += ldin(x, base + j * F_, bf);
  red[tid] = s; __syncthreads();
  for (int w = 128; w; w >>= 1) { if (tid < w) red[tid] += red[tid + w]; __syncthreads(); }
  float mean = red[0] / S_;
  __syncthreads();
  float v = 0.f;
  for (int j = tid; j < S_; j += 256) { float d = ldin(x, base + j * F_, bf) - mean; v += d * d; }
  red[tid] = v; __syncthreads();
  for (int w = 128; w; w >>= 1) { if (tid < w) red[tid] += red[tid + w]; __syncthreads(); }
  float inv = 1.f / (sqrtf(red[0] / (float)(S_ - 1)) + 1e-5f);
  for (int j = tid; j < S_; j += 256) xn[base + j * F_] = (ldin(x, base + j * F_, bf) - mean) * inv;
}

// ---------------- input projection + freq emb + positional encoding ----------------
__global__ __launch_bounds__(256) void input_proj_kernel(const float* __restrict__ xn,
                                                         const void* __restrict__ Wp,
                                                         const void* __restrict__ bp,
                                                         const void* __restrict__ femb,
                                                         const int* __restrict__ freq_idx,
                                                         float* __restrict__ h,
                                                         bf16* __restrict__ hb16,
                                                         const int* __restrict__ flag) {
  const int bf = flag[0];
  int idx = blockIdx.x * 256 + threadIdx.x;   // < T_*D_
  int d = idx % D_;
  int t = idx / D_;
  int s = t % S_;
  int fi = freq_idx[0];
  float acc = ldin(bp, d, bf) + ldin(femb, (size_t)fi * D_ + d, bf);
  int i2 = d & ~1;
  const float cexp = -9.2103403719761836f / (float)D_;   // -ln(10000)/D
  float ang = (float)s * expf((float)i2 * cexp);
  acc += (d & 1) ? cosf(ang) : sinf(ang);
  const float* xr = xn + t * F_;
#pragma unroll
  for (int f = 0; f < F_; f++) acc += xr[f] * ldin(Wp, (size_t)d * F_ + f, bf);
  h[idx] = acc;
  hb16[idx] = __float2bfloat16(acc);
}

// ---------------- MFMA GEMM: C[m,n] = sum_k A[m,k] * W[n,k] (+epilogue) ----------------
// 128x128 tile, BK=32, 4 waves x (4x4) mfma_f32_16x16x32_bf16. A is bf16 always.
// W is bf16 (flag=1, global_load_lds path) or fp32 (flag=0, convert path).
// Split-K via gridDim.z writes RAW bf16 PARTIAL SLICES (no atomics):
//   slice base = (bf16*)C_ + blockIdx.z * T_*D_ ; reduce_ln_kernel sums them later.
// MODE 0: partial slice store                                  (O-projection)
// MODE 3: C bf16 = acc + bias                                  (QKV)
// MODE 1: C bf16 = cw[m*4+eidx+(n>>10)] * relu(acc + bias[n])  (MoE mat1, expert pair)
// MODE 2: W virtual e=k>>10; partial slice store               (MoE mat2)
template <int MODE>
__global__ __launch_bounds__(256) void mfma_gemm(
    const bf16* __restrict__ A, const void* __restrict__ Wt, size_t woff,
    const void* __restrict__ bias, size_t boff, void* __restrict__ C_,
    int Kd, int lda, int ldb, int ldc,
    const float* __restrict__ cw, int eidx, const int* __restrict__ flag) {
  const int wbf = flag[0];
  __shared__ bf16 As[128][32];
  __shared__ bf16 Bs[128][32];
  const int tid = threadIdx.x;
  const int ln = tid & 63, wv = tid >> 6;
  const int n0 = blockIdx.x * 128;
  const int m0 = blockIdx.y * 128;
  const int wr = (wv >> 1) * 64, wc = (wv & 1) * 64;   // wave quadrant
  const int mrow = ln & 15, quad = ln >> 4;
  const int srow = ln >> 2;          // staging row-in-16 group
  const int skof = (ln & 3) * 8;     // staging k offset (elements)
  const int kchunk = Kd / gridDim.z;
  const int kbeg = blockIdx.z * kchunk;

  f32x4 acc[4][4];
#pragma unroll
  for (int i = 0; i < 4; i++)
#pragma unroll
    for (int j = 0; j < 4; j++) acc[i][j] = (f32x4){0.f, 0.f, 0.f, 0.f};

  for (int k0 = kbeg; k0 < kbeg + kchunk; k0 += 32) {
    // stage A: 2 x global_load_lds(16B) per thread
#pragma unroll
    for (int j = 0; j < 2; j++) {
      int row = 16 * (4 * j + wv) + srow;
      gload16(A + (size_t)(m0 + row) * lda + k0 + skof,
              (char*)&As[0][0] + (size_t)(4 * j + wv) * 1024);
    }
#pragma unroll
    for (int j = 0; j < 2; j++) {
      int row = 16 * (4 * j + wv) + srow;
      int kk = k0 + skof;
      size_t baddr;
      if (MODE == 2)
        baddr = woff + ((size_t)(kk >> 10) * 512 + (n0 + row)) * 1024 + (kk & 1023);
      else
        baddr = woff + (size_t)(n0 + row) * ldb + kk;
      if (wbf) {
        gload16((const bf16*)Wt + baddr, (char*)&Bs[0][0] + (size_t)(4 * j + wv) * 1024);
      } else {
        const float* g = (const float*)Wt + baddr;
        short8 v;
#pragma unroll
        for (int u = 0; u < 8; u++) {
          bf16 t = __float2bfloat16(g[u]);
          v[u] = *(short*)&t;
        }
        *(short8*)&Bs[row][skof] = v;
      }
    }
    __syncthreads();
    short8 af[4], bfr[4];
#pragma unroll
    for (int t = 0; t < 4; t++) {
      af[t]  = *(const short8*)&As[wr + t * 16 + mrow][quad * 8];
      bfr[t] = *(const short8*)&Bs[wc + t * 16 + mrow][quad * 8];
    }
#pragma unroll
    for (int i = 0; i < 4; i++)
#pragma unroll
      for (int j = 0; j < 4; j++)
        acc[i][j] = __builtin_amdgcn_mfma_f32_16x16x32_bf16(af[i], bfr[j], acc[i][j], 0, 0, 0);
    __syncthreads();
  }

  // epilogue: C/D layout col=lane&15, row=quad*4+reg
  bf16* slice = (MODE == 0 || MODE == 2)
                    ? (bf16*)C_ + (size_t)blockIdx.z * T_ * D_ : (bf16*)C_;
#pragma unroll
  for (int tj = 0; tj < 4; tj++) {
    int n = n0 + wc + tj * 16 + mrow;
    float bv = (MODE == 1 || MODE == 3) ? ldin(bias, boff + n, wbf) : 0.f;
#pragma unroll
    for (int ti = 0; ti < 4; ti++) {
      int mbase = m0 + wr + ti * 16 + quad * 4;
#pragma unroll
      for (int r = 0; r < 4; r++) {
        int m = mbase + r;
        float v = acc[ti][tj][r];
        if (MODE == 0 || MODE == 2) {
          slice[(size_t)m * ldc + n] = __float2bfloat16(v);
        } else if (MODE == 3) {
          slice[(size_t)m * ldc + n] = __float2bfloat16(v + bv);
        } else {   // MODE 1
          slice[(size_t)m * ldc + n] =
              __float2bfloat16(fmaxf(v + bv, 0.f) * cw[m * 4 + eidx + (n >> 10)]);
        }
      }
    }
  }
}

// ---------------- MFMA flash attention: one block per (b, h, 64-query tile) ---------
__global__ __launch_bounds__(256) void attn_kernel(const bf16* __restrict__ qkv,
                                                   bf16* __restrict__ o) {
  __shared__ bf16 Qs[64][72];
  __shared__ bf16 Ks[64][72];
  __shared__ bf16 Vt[64][72];   // [d][k]
  __shared__ bf16 Ps[64][72];   // [q][k]
  const int tid = threadIdx.x;
  const int ln = tid & 63, wv = tid >> 6;
  const int mrow = ln & 15, quad = ln >> 4;
  const int qt = blockIdx.x & 15, hh = (blockIdx.x >> 4) & 7, b = blockIdx.x >> 7;
  const int q0 = qt * 64;
  const int sr = tid >> 2;          // staging row 0..63
  const int sc = (tid & 3) * 8;     // staging col (elements); chunks at sc, sc+32

  // stage Q once: Qs[q][d]
  {
    const bf16* src = qkv + (size_t)(b * S_ + q0 + sr) * D3_ + hh * 64;
    *(short8*)&Qs[sr][sc]      = *(const short8*)(src + sc);
    *(short8*)&Qs[sr][sc + 32] = *(const short8*)(src + sc + 32);
  }
  __syncthreads();
  short8 aq[2];
  aq[0] = *(const short8*)&Qs[wv * 16 + mrow][quad * 8];
  aq[1] = *(const short8*)&Qs[wv * 16 + mrow][quad * 8 + 32];

  float m_st[4] = {-1e30f, -1e30f, -1e30f, -1e30f};
  float l_st[4] = {0.f, 0.f, 0.f, 0.f};
  f32x4 oacc[4];
#pragma unroll
  for (int t = 0; t < 4; t++) oacc[t] = (f32x4){0.f, 0.f, 0.f, 0.f};

  for (int kt = 0; kt < 16; kt++) {
    int k0 = kt * 64;
    __syncthreads();   // prev iteration's Vt reads (PV) and Ks reads (S) complete
    // stage K: Ks[k][d]
    {
      const bf16* src = qkv + (size_t)(b * S_ + k0 + sr) * D3_ + D_ + hh * 64;
      *(short8*)&Ks[sr][sc]      = *(const short8*)(src + sc);
      *(short8*)&Ks[sr][sc + 32] = *(const short8*)(src + sc + 32);
    }
    // stage V transposed: Vt[d][k]
    {
      const bf16* src = qkv + (size_t)(b * S_ + k0 + sr) * D3_ + 2 * D_ + hh * 64;
      short8 v0 = *(const short8*)(src + sc);
      short8 v1 = *(const short8*)(src + sc + 32);
#pragma unroll
      for (int u = 0; u < 8; u++) {
        *(short*)&Vt[sc + u][sr]      = v0[u];
        *(short*)&Vt[sc + 32 + u][sr] = v1[u];
      }
    }
    __syncthreads();
    // S tiles: wave's 16 q-rows x 64 keys
    f32x4 s[4];
#pragma unroll
    for (int t = 0; t < 4; t++) {
      s[t] = (f32x4){0.f, 0.f, 0.f, 0.f};
#pragma unroll
      for (int ks = 0; ks < 2; ks++) {
        short8 bk = *(const short8*)&Ks[t * 16 + mrow][quad * 8 + ks * 32];
        s[t] = __builtin_amdgcn_mfma_f32_16x16x32_bf16(aq[ks], bk, s[t], 0, 0, 0);
      }
    }
    // online softmax per row r (row q = wv*16 + quad*4 + r; 16 lanes share a row)
#pragma unroll
    for (int r = 0; r < 4; r++) {
      float rm = fmaxf(fmaxf(s[0][r], s[1][r]), fmaxf(s[2][r], s[3][r])) * 0.125f;
#pragma unroll
      for (int off = 8; off; off >>= 1) rm = fmaxf(rm, __shfl_xor(rm, off, 64));
      float mnew = fmaxf(m_st[r], rm);
      float alpha = __expf(m_st[r] - mnew);
      m_st[r] = mnew;
      float rs = 0.f;
#pragma unroll
      for (int t = 0; t < 4; t++) {
        float p = __expf(s[t][r] * 0.125f - mnew);
        rs += p;
        Ps[wv * 16 + quad * 4 + r][t * 16 + mrow] = __float2bfloat16(p);
      }
#pragma unroll
      for (int off = 8; off; off >>= 1) rs += __shfl_xor(rs, off, 64);
      l_st[r] = l_st[r] * alpha + rs;
#pragma unroll
      for (int t = 0; t < 4; t++) oacc[t][r] *= alpha;
    }
    // PV: rows of Ps written by this wave are exactly the rows it reads (no barrier)
    short8 ap[2];
    ap[0] = *(const short8*)&Ps[wv * 16 + mrow][quad * 8];
    ap[1] = *(const short8*)&Ps[wv * 16 + mrow][quad * 8 + 32];
#pragma unroll
    for (int t = 0; t < 4; t++) {
#pragma unroll
      for (int ks = 0; ks < 2; ks++) {
        short8 bv = *(const short8*)&Vt[t * 16 + mrow][quad * 8 + ks * 32];
        oacc[t] = __builtin_amdgcn_mfma_f32_16x16x32_bf16(ap[ks], bv, oacc[t], 0, 0, 0);
      }
    }
  }
  // epilogue: O[q][d] = oacc / l ; q = wv*16+quad*4+r, d = t*16+mrow
#pragma unroll
  for (int r = 0; r < 4; r++) {
    float inv = 1.f / l_st[r];
    size_t base = (size_t)(b * S_ + q0 + wv * 16 + quad * 4 + r) * D_ + hh * 64;
#pragma unroll
    for (int t = 0; t < 4; t++)
      o[base + t * 16 + mrow] = __float2bfloat16(oacc[t][r] * inv);
  }
}

// ---------------- fused: sum partial slices + bias + residual + LayerNorm ----------
// mode 0: biasadd = bias[n]              (O-projection; nsl slices)
// mode 1: biasadd = sum_e cw[t,e]*eb2[e,n]   (MoE; nsl slices)
__global__ __launch_bounds__(256) void reduce_ln_kernel(float* __restrict__ h,
                                                        bf16* __restrict__ hb16,
                                                        const bf16* __restrict__ ps,
                                                        int nsl, int mode,
                                                        const void* __restrict__ bias,
                                                        size_t boff,
                                                        const float* __restrict__ cw,
                                                        const void* __restrict__ eb2p,
                                                        size_t e2off,
                                                        const void* __restrict__ g,
                                                        const void* __restrict__ beta,
                                                        size_t off,
                                                        const int* __restrict__ flag) {
  const int bf = flag[0];
  int t = blockIdx.x, tid = threadIdx.x;
  __shared__ float r1[256], r2[256];
  const size_t base = (size_t)t * D_;
  float o0 = 0.f, o1 = 0.f;
  for (int s = 0; s < nsl; s++) {
    o0 += b2f(ps[(size_t)s * T_ * D_ + base + tid]);
    o1 += b2f(ps[(size_t)s * T_ * D_ + base + tid + 256]);
  }
  if (mode == 0) {
    o0 += ldin(bias, boff + tid, bf);
    o1 += ldin(bias, boff + tid + 256, bf);
  } else {
#pragma unroll
    for (int e = 0; e < 4; e++) {
      float w = cw[t * 4 + e];
      o0 += w * ldin(eb2p, e2off + e * D_ + tid, bf);
      o1 += w * ldin(eb2p, e2off + e * D_ + tid + 256, bf);
    }
  }
  float* hr = h + base;
  float v0 = hr[tid] + o0;
  float v1 = hr[tid + 256] + o1;
  r1[tid] = v0 + v1;
  r2[tid] = v0 * v0 + v1 * v1;
  __syncthreads();
  for (int w = 128; w; w >>= 1) { if (tid < w) { r1[tid] += r1[tid + w]; r2[tid] += r2[tid + w]; } __syncthreads(); }
  float mean = r1[0] * (1.f / D_);
  float var  = r2[0] * (1.f / D_) - mean * mean;
  float rstd = rsqrtf(var + 1e-5f);
  float n0 = (v0 - mean) * rstd * ldin(g, off + tid, bf) + ldin(beta, off + tid, bf);
  float n1 = (v1 - mean) * rstd * ldin(g, off + tid + 256, bf) + ldin(beta, off + tid + 256, bf);
  hr[tid] = n0;
  hr[tid + 256] = n1;
  hb16[base + tid] = __float2bfloat16(n0);
  hb16[base + tid + 256] = __float2bfloat16(n1);
}

// ---------------- MoE gating: softmax over E=4, top-2, renormalize ----------------
__global__ __launch_bounds__(256) void gate_kernel(const float* __restrict__ hbuf,
                                                   const void* __restrict__ gw, size_t gwoff,
                                                   const void* __restrict__ gb, size_t gboff,
                                                   float* __restrict__ cw,
                                                   const int* __restrict__ flag) {
  const int bf = flag[0];
  int lane = threadIdx.x & 63, wv = threadIdx.x >> 6;
  int t = blockIdx.x * 4 + wv;
  const float* xr = hbuf + (size_t)t * D_;
  float a[4] = {0, 0, 0, 0};
  for (int d = lane; d < D_; d += 64) {
    float xv = xr[d];
#pragma unroll
    for (int e = 0; e < 4; e++) a[e] += xv * ldin(gw, gwoff + e * D_ + d, bf);
  }
#pragma unroll
  for (int e = 0; e < 4; e++)
    for (int off = 32; off; off >>= 1) a[e] += __shfl_xor(a[e], off, 64);
  if (lane == 0) {
    float lg[4];
#pragma unroll
    for (int e = 0; e < 4; e++) lg[e] = a[e] + ldin(gb, gboff + e, bf);
    float m = fmaxf(fmaxf(lg[0], lg[1]), fmaxf(lg[2], lg[3]));
    float p[4], s = 0.f;
#pragma unroll
    for (int e = 0; e < 4; e++) { p[e] = __expf(lg[e] - m); s += p[e]; }
#pragma unroll
    for (int e = 0; e < 4; e++) p[e] /= s;
    int i0 = 0;
    for (int e = 1; e < 4; e++) if (p[e] > p[i0]) i0 = e;   // first occurrence on ties
    int i1 = -1;
    for (int e = 0; e < 4; e++) if (e != i0 && (i1 < 0 || p[e] > p[i1])) i1 = e;
    float s2 = p[i0] + p[i1];
    float outw[4] = {0, 0, 0, 0};
    outw[i0] = p[i0] / s2;
    outw[i1] = p[i1] / s2;
#pragma unroll
    for (int e = 0; e < 4; e++) cw[t * 4 + e] = outw[e];
  }
}

// ---------------- head: out[b,q] = dot(h[b,-1,:], hw[q,:]) + hb[q] ----------------
__global__ __launch_bounds__(256) void head_kernel(const float* __restrict__ hbuf,
                                                   const void* __restrict__ hw,
                                                   const void* __restrict__ hb,
                                                   void* __restrict__ out,
                                                   const int* __restrict__ flag) {
  const int bf = flag[0];
  int bq = blockIdx.x, tid = threadIdx.x;
  int b = bq / 3, q = bq % 3;
  __shared__ float red[256];
  const float* xr = hbuf + (size_t)(b * S_ + (S_ - 1)) * D_;
  float sacc = xr[tid] * ldin(hw, (size_t)q * D_ + tid, bf)
             + xr[tid + 256] * ldin(hw, (size_t)q * D_ + tid + 256, bf);
  red[tid] = sacc; __syncthreads();
  for (int w = 128; w; w >>= 1) { if (tid < w) red[tid] += red[tid + w]; __syncthreads(); }
  if (tid == 0) {
    float r = red[0] + ldin(hb, q, bf);
    if (bf) ((bf16*)out)[bq] = __float2bfloat16(r);
    else    ((float*)out)[bq] = r;
  }
}

extern "C" void kernel_launch(void* const* d_in, const int* in_sizes, int n_in,
                              void* d_out, int out_size, void* d_ws, size_t ws_size,
                              hipStream_t stream) {
  const void* x    = d_in[0];
  const void* Wp   = d_in[1];
  const void* bp   = d_in[2];
  const void* femb = d_in[3];
  const void* qkvw = d_in[4];
  const void* qkvb = d_in[5];
  const void* ow   = d_in[6];
  const void* ob   = d_in[7];
  const void* g1   = d_in[8];
  const void* be1  = d_in[9];
  const void* gw   = d_in[10];
  const void* gb   = d_in[11];
  const void* ew1  = d_in[12];
  const void* eb1  = d_in[13];
  const void* ew2  = d_in[14];
  const void* eb2  = d_in[15];
  const void* g2   = d_in[16];
  const void* be2  = d_in[17];
  const void* hw   = d_in[18];
  const void* hb   = d_in[19];
  const int*  freq = (const int*)d_in[20];

  // workspace layout: ~88 MB peak (proven-safe bound: 101 MB)
  int*   flag = (int*)d_ws;
  float* xn   = (float*)d_ws + 64;                  // 65536 f
  float* h    = xn + 65536;                         // T*D f       (16 MB)
  float* cw   = h + (size_t)T_ * D_;                // T*4 f
  bf16*  hb16 = (bf16*)(cw + (size_t)T_ * E_);      // T*D bf16    (8 MB)
  bf16*  qkvb16 = hb16 + (size_t)T_ * D_;           // T*3D bf16   (24 MB)
  bf16*  ao   = qkvb16 + (size_t)T_ * D3_;          // T*D bf16    (8 MB)
  bf16*  psl  = ao + (size_t)T_ * D_;               // 4x T*D bf16 (32 MB partial slices)
  bf16*  hid  = qkvb16;                             // T*2048 bf16 (32 MB = qkv+ao exactly)

  detect_kernel<<<1, 64, 0, stream>>>(x, flag);
  instnorm_kernel<<<B_ * F_, 256, 0, stream>>>(x, xn, flag);
  input_proj_kernel<<<(T_ * D_) / 256, 256, 0, stream>>>(xn, Wp, bp, femb, freq, h, hb16, flag);

  for (int l = 0; l < 3; l++) {
    // QKV projection -> bf16 qkv
    mfma_gemm<3><<<dim3(D3_ / 128, T_ / 128), 256, 0, stream>>>(
        hb16, qkvw, (size_t)l * D3_ * D_, qkvb, (size_t)l * D3_, qkvb16,
        D_, D_, D_, D3_, nullptr, 0, flag);
    attn_kernel<<<B_ * H_ * (S_ / 64), 256, 0, stream>>>(qkvb16, ao);
    // O-projection: split-K=2 -> partial slices 0,1; fused reduce + bias + LN
    mfma_gemm<0><<<dim3(D_ / 128, T_ / 128, 2), 256, 0, stream>>>(
        ao, ow, (size_t)l * D_ * D_, nullptr, 0, psl,
        D_, D_, D_, D_, nullptr, 0, flag);
    reduce_ln_kernel<<<T_, 256, 0, stream>>>(
        h, hb16, psl, 2, 0, ob, (size_t)l * D_, nullptr, nullptr, 0,
        g1, be1, (size_t)l * D_, flag);
    gate_kernel<<<T_ / 4, 256, 0, stream>>>(h, gw, (size_t)l * E_ * D_, gb, (size_t)l * E_, cw, flag);
    // MoE: per expert-pair mat1 + split-K=2 mat2 into slices {2p, 2p+1}
    for (int pair = 0; pair < 2; pair++) {
      // mat1: hid[T,2048] = cw * relu(hb16 @ ew1[l, 2p:2p+2]^T + eb1)
      mfma_gemm<1><<<dim3(2048 / 128, T_ / 128), 256, 0, stream>>>(
          hb16, ew1, ((size_t)l * 4 + pair * 2) * 1024 * 512, eb1,
          (size_t)l * 4096 + pair * 2048, hid,
          D_, D_, D_, 2048, cw, pair * 2, flag);
      // mat2: slices[2p+z] = hid @ W2pair^T chunk z (K=2048 virtual, split-K=2)
      mfma_gemm<2><<<dim3(D_ / 128, T_ / 128, 2), 256, 0, stream>>>(
          hid, ew2, ((size_t)l * 4 + pair * 2) * 512 * 1024, nullptr, 0,
          psl + (size_t)pair * 2 * T_ * D_,
          2048, 2048, 0, D_, nullptr, pair, flag);
    }
    reduce_ln_kernel<<<T_, 256, 0, stream>>>(
        h, hb16, psl, 4, 1, nullptr, 0, cw, eb2, (size_t)l * 4 * D_,
        g2, be2, (size_t)l * D_, flag);
  }

  head_kernel<<<24, 256, 0, stream>>>(h, hw, hb, d_out, flag);
}

// Round 8
// 1152.181 us; speedup vs baseline: 17.3622x; 1.1999x over previous
//
#include <hip/hip_runtime.h>
#include <hip/hip_bf16.h>
#include <math.h>

typedef __hip_bfloat16 bf16;
typedef __attribute__((ext_vector_type(8))) short short8;   // 8 bf16 (4 VGPRs)
typedef __attribute__((ext_vector_type(4))) float f32x4;

constexpr int B_ = 8, S_ = 1024, F_ = 8, D_ = 512, H_ = 8, E_ = 4;
constexpr int T_  = B_ * S_;       // 8192 tokens
constexpr int D3_ = 3 * D_;        // 1536
constexpr int CAP_ = T_ * 2 + E_ * 128;   // sparse row capacity (top-2, 128-pad/expert)

__device__ __forceinline__ float b2f(bf16 v) { return __bfloat162float(v); }
__device__ __forceinline__ float ldin(const void* p, size_t i, int bf) {
  return bf ? __bfloat162float(((const bf16*)p)[i]) : ((const float*)p)[i];
}
__device__ __forceinline__ void gload16(const void* g, void* l) {
  __builtin_amdgcn_global_load_lds((const __attribute__((address_space(1))) unsigned int*)g,
                                   (__attribute__((address_space(3))) unsigned int*)l, 16, 0, 0);
}

// ---------------- dtype detector ----------------
__global__ void detect_kernel(const void* __restrict__ x, int* __restrict__ flag) {
  if (threadIdx.x == 0 && blockIdx.x == 0) {
    const unsigned short* u = (const unsigned short*)x;
    int c = 0;
    for (int i = 0; i < 256; i += 2) {
      int ex = (u[i] >> 7) & 0xFF;
      if (ex >= 96 && ex <= 144) c++;
    }
    flag[0] = (c >= 64) ? 1 : 0;
  }
}

// ---------------- instance norm over time axis ----------------
__global__ __launch_bounds__(256) void instnorm_kernel(const void* __restrict__ x,
                                                       float* __restrict__ xn,
                                                       const int* __restrict__ flag) {
  const int bf = flag[0];
  int b = blockIdx.x / F_, f = blockIdx.x % F_;
  int tid = threadIdx.x;
  __shared__ float red[256];
  const int base = b * S_ * F_ + f;
  float s = 0.f;
  for (int j = tid; j < S_; j += 256) s += ldin(x, base + j * F_, bf);
  red[tid] = s; __syncthreads();
  for (int w = 128; w; w >>= 1) { if (tid < w) red[tid] += red[tid + w]; __syncthreads(); }
  float mean = red[0] / S_;
  __syncthreads();
  float v = 0.f;
  for (int j = tid; j < S_; j += 256) { float d = ldin(x, base + j * F_, bf) - mean; v += d * d; }
  red[tid] = v; __syncthreads();
  for (int w = 128; w; w >>= 1) { if (tid < w) red[tid] += red[tid + w]; __syncthreads(); }
  float inv = 1.f / (sqrtf(red[0] / (float)(S_ - 1)) + 1e-5f);
  for (int j = tid; j < S_; j += 256) xn[base + j * F_] = (ldin(x, base + j * F_, bf) - mean) * inv;
}

// ---------------- input projection + freq emb + positional encoding ----------------
__global__ __launch_bounds__(256) void input_proj_kernel(const float* __restrict__ xn,
                                                         const void* __restrict__ Wp,
                                                         const void* __restrict__ bp,
                                                         const void* __restrict__ femb,
                                                         const int* __restrict__ freq_idx,
                                                         float* __restrict__ h,
                                                         bf16* __restrict__ hb16,
                                                         const int* __restrict__ flag) {
  const int bf = flag[0];
  int idx = blockIdx.x * 256 + threadIdx.x;
  int d = idx % D_;
  int t = idx / D_;
  int s = t % S_;
  int fi = freq_idx[0];
  float acc = ldin(bp, d, bf) + ldin(femb, (size_t)fi * D_ + d, bf);
  int i2 = d & ~1;
  const float cexp = -9.2103403719761836f / (float)D_;
  float ang = (float)s * expf((float)i2 * cexp);
  acc += (d & 1) ? cosf(ang) : sinf(ang);
  const float* xr = xn + t * F_;
#pragma unroll
  for (int f = 0; f < F_; f++) acc += xr[f] * ldin(Wp, (size_t)d * F_ + f, bf);
  h[idx] = acc;
  hb16[idx] = __float2bfloat16(acc);
}

// ---------------- dense MFMA GEMM (QKV / O-proj) ----------------
// MODE 3: C bf16 = acc + bias  (QKV). MODE 0: partial bf16 slice per z (O-proj).
template <int MODE>
__global__ __launch_bounds__(256) void mfma_gemm(
    const bf16* __restrict__ A, const void* __restrict__ Wt, size_t woff,
    const void* __restrict__ bias, size_t boff, void* __restrict__ C_,
    int Kd, int lda, int ldb, int ldc, const int* __restrict__ flag) {
  const int wbf = flag[0];
  __shared__ bf16 As[128][32];
  __shared__ bf16 Bs[128][32];
  const int tid = threadIdx.x;
  const int ln = tid & 63, wv = tid >> 6;
  const int n0 = blockIdx.x * 128;
  const int m0 = blockIdx.y * 128;
  const int wr = (wv >> 1) * 64, wc = (wv & 1) * 64;
  const int mrow = ln & 15, quad = ln >> 4;
  const int srow = ln >> 2;
  const int skof = (ln & 3) * 8;
  const int kchunk = Kd / gridDim.z;
  const int kbeg = blockIdx.z * kchunk;

  f32x4 acc[4][4];
#pragma unroll
  for (int i = 0; i < 4; i++)
#pragma unroll
    for (int j = 0; j < 4; j++) acc[i][j] = (f32x4){0.f, 0.f, 0.f, 0.f};

  for (int k0 = kbeg; k0 < kbeg + kchunk; k0 += 32) {
#pragma unroll
    for (int j = 0; j < 2; j++) {
      int row = 16 * (4 * j + wv) + srow;
      gload16(A + (size_t)(m0 + row) * lda + k0 + skof,
              (char*)&As[0][0] + (size_t)(4 * j + wv) * 1024);
    }
#pragma unroll
    for (int j = 0; j < 2; j++) {
      int row = 16 * (4 * j + wv) + srow;
      int kk = k0 + skof;
      size_t baddr = woff + (size_t)(n0 + row) * ldb + kk;
      if (wbf) {
        gload16((const bf16*)Wt + baddr, (char*)&Bs[0][0] + (size_t)(4 * j + wv) * 1024);
      } else {
        const float* g = (const float*)Wt + baddr;
        short8 v;
#pragma unroll
        for (int u = 0; u < 8; u++) { bf16 t = __float2bfloat16(g[u]); v[u] = *(short*)&t; }
        *(short8*)&Bs[row][skof] = v;
      }
    }
    __syncthreads();
    short8 af[4], bfr[4];
#pragma unroll
    for (int t = 0; t < 4; t++) {
      af[t]  = *(const short8*)&As[wr + t * 16 + mrow][quad * 8];
      bfr[t] = *(const short8*)&Bs[wc + t * 16 + mrow][quad * 8];
    }
#pragma unroll
    for (int i = 0; i < 4; i++)
#pragma unroll
      for (int j = 0; j < 4; j++)
        acc[i][j] = __builtin_amdgcn_mfma_f32_16x16x32_bf16(af[i], bfr[j], acc[i][j], 0, 0, 0);
    __syncthreads();
  }

  bf16* slice = (MODE == 0) ? (bf16*)C_ + (size_t)blockIdx.z * T_ * D_ : (bf16*)C_;
#pragma unroll
  for (int tj = 0; tj < 4; tj++) {
    int n = n0 + wc + tj * 16 + mrow;
    float bv = (MODE == 3) ? ldin(bias, boff + n, wbf) : 0.f;
#pragma unroll
    for (int ti = 0; ti < 4; ti++) {
      int mbase = m0 + wr + ti * 16 + quad * 4;
#pragma unroll
      for (int r = 0; r < 4; r++) {
        int m = mbase + r;
        float v = acc[ti][tj][r];
        slice[(size_t)m * ldc + n] = __float2bfloat16(MODE == 3 ? v + bv : v);
      }
    }
  }
}

// ---------------- MFMA flash attention: 128-query tile, swizzled V transpose --------
__global__ __launch_bounds__(256) void attn_kernel(const bf16* __restrict__ qkv,
                                                   bf16* __restrict__ o) {
  __shared__ bf16 Qs[128][72];
  __shared__ bf16 Ks[64][72];
  __shared__ bf16 Vt[64][72];    // [d][k ^ swz(d)]
  __shared__ bf16 Ps[128][72];   // [q][k]
  const int tid = threadIdx.x;
  const int ln = tid & 63, wv = tid >> 6;
  const int mrow = ln & 15, quad = ln >> 4;
  const int qt = blockIdx.x & 7, hh = (blockIdx.x >> 3) & 7, b = blockIdx.x >> 6;
  const int q0 = qt * 128;
  const int sr = tid >> 2;          // staging row 0..63
  const int sg = tid & 3;           // staging col group
  const int sc = sg * 8;            // staging col base; chunks at sc, sc+32

  // stage Q (128 rows, two passes)
#pragma unroll
  for (int p = 0; p < 2; p++) {
    int row = sr + p * 64;
    const bf16* src = qkv + (size_t)(b * S_ + q0 + row) * D3_ + hh * 64;
    *(short8*)&Qs[row][sc]      = *(const short8*)(src + sc);
    *(short8*)&Qs[row][sc + 32] = *(const short8*)(src + sc + 32);
  }
  __syncthreads();
  short8 aq[2][2];
#pragma unroll
  for (int g = 0; g < 2; g++) {
    aq[g][0] = *(const short8*)&Qs[wv * 32 + g * 16 + mrow][quad * 8];
    aq[g][1] = *(const short8*)&Qs[wv * 32 + g * 16 + mrow][quad * 8 + 32];
  }

  float m_st[2][4], l_st[2][4];
  f32x4 oacc[2][4];
#pragma unroll
  for (int g = 0; g < 2; g++)
#pragma unroll
    for (int t = 0; t < 4; t++) {
      m_st[g][t] = -1e30f; l_st[g][t] = 0.f;
      oacc[g][t] = (f32x4){0.f, 0.f, 0.f, 0.f};
    }

  for (int kt = 0; kt < 16; kt++) {
    int k0 = kt * 64;
    __syncthreads();
    // stage K: Ks[k][d]
    {
      const bf16* src = qkv + (size_t)(b * S_ + k0 + sr) * D3_ + D_ + hh * 64;
      *(short8*)&Ks[sr][sc]      = *(const short8*)(src + sc);
      *(short8*)&Ks[sr][sc + 32] = *(const short8*)(src + sc + 32);
    }
    // stage V transposed with XOR swizzle: Vt[d][k ^ ((d>>3)&3)*16]
    {
      const bf16* src = qkv + (size_t)(b * S_ + k0 + sr) * D3_ + 2 * D_ + hh * 64;
      short8 v0 = *(const short8*)(src + sc);
      short8 v1 = *(const short8*)(src + sc + 32);
      int col0 = sr ^ (sg << 4);          // swz for d in [sc, sc+8): (d>>3)&3 == sg
      int col1 = sr ^ (((sg + 4) & 3) << 4);   // d in [sc+32, sc+40): group sg+4
#pragma unroll
      for (int u = 0; u < 8; u++) {
        *(short*)&Vt[sc + u][col0]      = v0[u];
        *(short*)&Vt[sc + 32 + u][col1] = v1[u];
      }
    }
    __syncthreads();
    // S tiles: 32 q-rows per wave x 64 keys
    f32x4 s[2][4];
#pragma unroll
    for (int g = 0; g < 2; g++)
#pragma unroll
      for (int t = 0; t < 4; t++) {
        s[g][t] = (f32x4){0.f, 0.f, 0.f, 0.f};
#pragma unroll
        for (int ks = 0; ks < 2; ks++) {
          short8 bk = *(const short8*)&Ks[t * 16 + mrow][quad * 8 + ks * 32];
          s[g][t] = __builtin_amdgcn_mfma_f32_16x16x32_bf16(aq[g][ks], bk, s[g][t], 0, 0, 0);
        }
      }
    // online softmax (row q = wv*32 + g*16 + quad*4 + r; 16 lanes share a row)
#pragma unroll
    for (int g = 0; g < 2; g++)
#pragma unroll
      for (int r = 0; r < 4; r++) {
        float rm = fmaxf(fmaxf(s[g][0][r], s[g][1][r]), fmaxf(s[g][2][r], s[g][3][r])) * 0.125f;
#pragma unroll
        for (int off = 8; off; off >>= 1) rm = fmaxf(rm, __shfl_xor(rm, off, 64));
        float mnew = fmaxf(m_st[g][r], rm);
        float alpha = __expf(m_st[g][r] - mnew);
        m_st[g][r] = mnew;
        float rs = 0.f;
#pragma unroll
        for (int t = 0; t < 4; t++) {
          float p = __expf(s[g][t][r] * 0.125f - mnew);
          rs += p;
          Ps[wv * 32 + g * 16 + quad * 4 + r][t * 16 + mrow] = __float2bfloat16(p);
        }
#pragma unroll
        for (int off = 8; off; off >>= 1) rs += __shfl_xor(rs, off, 64);
        l_st[g][r] = l_st[g][r] * alpha + rs;
#pragma unroll
        for (int t = 0; t < 4; t++) oacc[g][t][r] *= alpha;
      }
    // PV (Ps rows written by this wave == rows it reads; no barrier needed)
#pragma unroll
    for (int g = 0; g < 2; g++) {
      short8 ap[2];
      ap[0] = *(const short8*)&Ps[wv * 32 + g * 16 + mrow][quad * 8];
      ap[1] = *(const short8*)&Ps[wv * 32 + g * 16 + mrow][quad * 8 + 32];
#pragma unroll
      for (int t = 0; t < 4; t++) {
        int d = t * 16 + mrow;
        int swz = ((d >> 3) & 3) << 4;
#pragma unroll
        for (int ks = 0; ks < 2; ks++) {
          short8 bv = *(const short8*)&Vt[d][(quad * 8 + ks * 32) ^ swz];
          oacc[g][t] = __builtin_amdgcn_mfma_f32_16x16x32_bf16(ap[ks], bv, oacc[g][t], 0, 0, 0);
        }
      }
    }
  }
  // epilogue
#pragma unroll
  for (int g = 0; g < 2; g++)
#pragma unroll
    for (int r = 0; r < 4; r++) {
      float inv = 1.f / l_st[g][r];
      size_t base = (size_t)(b * S_ + q0 + wv * 32 + g * 16 + quad * 4 + r) * D_ + hh * 64;
#pragma unroll
      for (int t = 0; t < 4; t++)
        o[base + t * 16 + mrow] = __float2bfloat16(oacc[g][t][r] * inv);
    }
}

// ---------------- fused: sum partial slices + bias + residual + LayerNorm ----------
__global__ __launch_bounds__(256) void reduce_ln_kernel(float* __restrict__ h,
                                                        bf16* __restrict__ hb16,
                                                        const bf16* __restrict__ ps,
                                                        int nsl, int mode,
                                                        const void* __restrict__ bias,
                                                        size_t boff,
                                                        const float* __restrict__ cw,
                                                        const void* __restrict__ eb2p,
                                                        size_t e2off,
                                                        const void* __restrict__ g,
                                                        const void* __restrict__ beta,
                                                        size_t off,
                                                        const int* __restrict__ flag) {
  const int bf = flag[0];
  int t = blockIdx.x, tid = threadIdx.x;
  __shared__ float r1[256], r2[256];
  const size_t base = (size_t)t * D_;
  float o0 = 0.f, o1 = 0.f;
  for (int s = 0; s < nsl; s++) {
    o0 += b2f(ps[(size_t)s * T_ * D_ + base + tid]);
    o1 += b2f(ps[(size_t)s * T_ * D_ + base + tid + 256]);
  }
  if (mode == 0) {
    o0 += ldin(bias, boff + tid, bf);
    o1 += ldin(bias, boff + tid + 256, bf);
  } else {
#pragma unroll
    for (int e = 0; e < 4; e++) {
      float w = cw[t * 4 + e];
      o0 += w * ldin(eb2p, e2off + e * D_ + tid, bf);
      o1 += w * ldin(eb2p, e2off + e * D_ + tid + 256, bf);
    }
  }
  float* hr = h + base;
  float v0 = hr[tid] + o0;
  float v1 = hr[tid + 256] + o1;
  r1[tid] = v0 + v1;
  r2[tid] = v0 * v0 + v1 * v1;
  __syncthreads();
  for (int w = 128; w; w >>= 1) { if (tid < w) { r1[tid] += r1[tid + w]; r2[tid] += r2[tid + w]; } __syncthreads(); }
  float mean = r1[0] * (1.f / D_);
  float var  = r2[0] * (1.f / D_) - mean * mean;
  float rstd = rsqrtf(var + 1e-5f);
  float n0 = (v0 - mean) * rstd * ldin(g, off + tid, bf) + ldin(beta, off + tid, bf);
  float n1 = (v1 - mean) * rstd * ldin(g, off + tid + 256, bf) + ldin(beta, off + tid + 256, bf);
  hr[tid] = n0;
  hr[tid + 256] = n1;
  hb16[base + tid] = __float2bfloat16(n0);
  hb16[base + tid + 256] = __float2bfloat16(n1);
}

// ---------------- MoE gating: softmax over E=4, top-2; emits routing info ----------
__global__ __launch_bounds__(256) void gate_kernel(const float* __restrict__ hbuf,
                                                   const void* __restrict__ gw, size_t gwoff,
                                                   const void* __restrict__ gb, size_t gboff,
                                                   float* __restrict__ cw,
                                                   int* __restrict__ einfo,
                                                   float* __restrict__ w0a,
                                                   float* __restrict__ w1a,
                                                   const int* __restrict__ flag) {
  const int bf = flag[0];
  int lane = threadIdx.x & 63, wv = threadIdx.x >> 6;
  int t = blockIdx.x * 4 + wv;
  const float* xr = hbuf + (size_t)t * D_;
  float a[4] = {0, 0, 0, 0};
  for (int d = lane; d < D_; d += 64) {
    float xv = xr[d];
#pragma unroll
    for (int e = 0; e < 4; e++) a[e] += xv * ldin(gw, gwoff + e * D_ + d, bf);
  }
#pragma unroll
  for (int e = 0; e < 4; e++)
    for (int off = 32; off; off >>= 1) a[e] += __shfl_xor(a[e], off, 64);
  if (lane == 0) {
    float lg[4];
#pragma unroll
    for (int e = 0; e < 4; e++) lg[e] = a[e] + ldin(gb, gboff + e, bf);
    float m = fmaxf(fmaxf(lg[0], lg[1]), fmaxf(lg[2], lg[3]));
    float p[4], s = 0.f;
#pragma unroll
    for (int e = 0; e < 4; e++) { p[e] = __expf(lg[e] - m); s += p[e]; }
#pragma unroll
    for (int e = 0; e < 4; e++) p[e] /= s;
    int i0 = 0;
    for (int e = 1; e < 4; e++) if (p[e] > p[i0]) i0 = e;
    int i1 = -1;
    for (int e = 0; e < 4; e++) if (e != i0 && (i1 < 0 || p[e] > p[i1])) i1 = e;
    float s2 = p[i0] + p[i1];
    float ww0 = p[i0] / s2, ww1 = p[i1] / s2;
    float outw[4] = {0, 0, 0, 0};
    outw[i0] = ww0; outw[i1] = ww1;
#pragma unroll
    for (int e = 0; e < 4; e++) cw[t * 4 + e] = outw[e];
    einfo[t] = i0 | (i1 << 4);
    w0a[t] = ww0; w1a[t] = ww1;
  }
}

// ---------------- route scan: counts -> 128-aligned offsets (1 block) ----------------
__global__ __launch_bounds__(256) void route_scan_kernel(const int* __restrict__ einfo,
                                                         int* __restrict__ off,
                                                         int* __restrict__ endp,
                                                         int* __restrict__ cur) {
  __shared__ int red[4][256];
  int tid = threadIdx.x;
  int c[4] = {0, 0, 0, 0};
  for (int t = tid; t < T_; t += 256) {
    int inf = einfo[t];
    c[inf & 15]++;
    c[(inf >> 4) & 15]++;
  }
#pragma unroll
  for (int e = 0; e < 4; e++) red[e][tid] = c[e];
  __syncthreads();
  for (int w = 128; w; w >>= 1) {
    if (tid < w)
#pragma unroll
      for (int e = 0; e < 4; e++) red[e][tid] += red[e][tid + w];
    __syncthreads();
  }
  if (tid == 0) {
    int o = 0;
#pragma unroll
    for (int e = 0; e < 4; e++) {
      int cnt = red[e][0];
      off[e] = o;
      endp[e] = o + cnt;
      cur[e] = 0;
      o += ((cnt + 127) / 128) * 128;
    }
  }
}

// ---------------- scatter: token -> (expert bucket, rank), ballot-aggregated --------
__global__ __launch_bounds__(256) void scatter_kernel(const int* __restrict__ einfo,
                                                      const float* __restrict__ w0a,
                                                      const float* __restrict__ w1a,
                                                      const int* __restrict__ off,
                                                      int* __restrict__ cur,
                                                      int* __restrict__ pack,
                                                      float* __restrict__ wlist) {
  int t = blockIdx.x * 256 + threadIdx.x;
  int lane = threadIdx.x & 63;
  int inf = einfo[t];
#pragma unroll
  for (int rank = 0; rank < 2; rank++) {
    int my_e = (rank == 0) ? (inf & 15) : ((inf >> 4) & 15);
    float w = (rank == 0) ? w0a[t] : w1a[t];
#pragma unroll
    for (int e = 0; e < 4; e++) {
      bool p = (my_e == e);
      unsigned long long mask = __ballot(p);
      if (!mask) continue;
      int leader = __ffsll((long long)mask) - 1;
      int base = 0;
      if (lane == leader) base = atomicAdd(&cur[e], (int)__popcll(mask));
      base = __shfl(base, leader, 64);
      if (p) {
        int pos = off[e] + base + (int)__popcll(mask & ((1ULL << lane) - 1ULL));
        pack[pos] = t * 2 + rank;
        wlist[pos] = w;
      }
    }
  }
}

// ---------------- sparse MoE mat1: hid[pos,:] = w * relu(x[tok] @ ew1[e]^T + eb1[e]) --
__global__ __launch_bounds__(256) void moe_mat1_kernel(
    const bf16* __restrict__ A, const void* __restrict__ Wt, size_t woff,
    const void* __restrict__ bias, size_t boff, bf16* __restrict__ hid,
    const int* __restrict__ off, const int* __restrict__ endp,
    const int* __restrict__ pack, const float* __restrict__ wlist,
    const int* __restrict__ flag) {
  const int wbf = flag[0];
  const int e = blockIdx.y >> 6, mt = blockIdx.y & 63;
  const int o = off[e], en = endp[e];
  if (mt * 128 >= en - o) return;
  __shared__ bf16 As[128][32];
  __shared__ bf16 Bs[128][32];
  const int tid = threadIdx.x;
  const int ln = tid & 63, wv = tid >> 6;
  const int n0 = blockIdx.x * 128;
  const int m0 = o + mt * 128;
  const int wr = (wv >> 1) * 64, wc = (wv & 1) * 64;
  const int mrow = ln & 15, quad = ln >> 4;
  const int srow = ln >> 2;
  const int skof = (ln & 3) * 8;
  // gather source tokens for this thread's two staged rows
  int tokr[2];
#pragma unroll
  for (int j = 0; j < 2; j++) {
    int pos = m0 + 16 * (4 * j + wv) + srow;
    tokr[j] = pack[min(pos, en - 1)] >> 1;
  }

  f32x4 acc[4][4];
#pragma unroll
  for (int i = 0; i < 4; i++)
#pragma unroll
    for (int j = 0; j < 4; j++) acc[i][j] = (f32x4){0.f, 0.f, 0.f, 0.f};

  const size_t wbase = woff + (size_t)e * 1024 * 512;
  for (int k0 = 0; k0 < 512; k0 += 32) {
#pragma unroll
    for (int j = 0; j < 2; j++)
      gload16(A + (size_t)tokr[j] * 512 + k0 + skof,
              (char*)&As[0][0] + (size_t)(4 * j + wv) * 1024);
#pragma unroll
    for (int j = 0; j < 2; j++) {
      int row = 16 * (4 * j + wv) + srow;
      size_t baddr = wbase + (size_t)(n0 + row) * 512 + k0 + skof;
      if (wbf) {
        gload16((const bf16*)Wt + baddr, (char*)&Bs[0][0] + (size_t)(4 * j + wv) * 1024);
      } else {
        const float* g = (const float*)Wt + baddr;
        short8 v;
#pragma unroll
        for (int u = 0; u < 8; u++) { bf16 t = __float2bfloat16(g[u]); v[u] = *(short*)&t; }
        *(short8*)&Bs[row][skof] = v;
      }
    }
    __syncthreads();
    short8 af[4], bfr[4];
#pragma unroll
    for (int t = 0; t < 4; t++) {
      af[t]  = *(const short8*)&As[wr + t * 16 + mrow][quad * 8];
      bfr[t] = *(const short8*)&Bs[wc + t * 16 + mrow][quad * 8];
    }
#pragma unroll
    for (int i = 0; i < 4; i++)
#pragma unroll
      for (int j = 0; j < 4; j++)
        acc[i][j] = __builtin_amdgcn_mfma_f32_16x16x32_bf16(af[i], bfr[j], acc[i][j], 0, 0, 0);
    __syncthreads();
  }

#pragma unroll
  for (int ti = 0; ti < 4; ti++) {
#pragma unroll
    for (int r = 0; r < 4; r++) {
      int pos = m0 + wr + ti * 16 + quad * 4 + r;
      float w = (pos < en) ? wlist[pos] : 0.f;
#pragma unroll
      for (int tj = 0; tj < 4; tj++) {
        int ncol = n0 + wc + tj * 16 + mrow;
        float v = acc[ti][tj][r] + ldin(bias, boff + e * 1024 + ncol, wbf);
        hid[(size_t)pos * 1024 + ncol] = __float2bfloat16(fmaxf(v, 0.f) * w);
      }
    }
  }
}

// ---------------- sparse MoE mat2: psl[rank*2+z][tok,:] = hid[pos,:] @ ew2[e]^T ------
__global__ __launch_bounds__(256) void moe_mat2_kernel(
    const bf16* __restrict__ hid, const void* __restrict__ Wt, size_t woff,
    bf16* __restrict__ psl,
    const int* __restrict__ off, const int* __restrict__ endp,
    const int* __restrict__ pack, const int* __restrict__ flag) {
  const int wbf = flag[0];
  const int e = blockIdx.y >> 6, mt = blockIdx.y & 63;
  const int o = off[e], en = endp[e];
  if (mt * 128 >= en - o) return;
  __shared__ bf16 As[128][32];
  __shared__ bf16 Bs[128][32];
  const int tid = threadIdx.x;
  const int ln = tid & 63, wv = tid >> 6;
  const int n0 = blockIdx.x * 128;
  const int m0 = o + mt * 128;
  const int wr = (wv >> 1) * 64, wc = (wv & 1) * 64;
  const int mrow = ln & 15, quad = ln >> 4;
  const int srow = ln >> 2;
  const int skof = (ln & 3) * 8;
  const int kbeg = blockIdx.z * 512;

  f32x4 acc[4][4];
#pragma unroll
  for (int i = 0; i < 4; i++)
#pragma unroll
    for (int j = 0; j < 4; j++) acc[i][j] = (f32x4){0.f, 0.f, 0.f, 0.f};

  const size_t wbase = woff + (size_t)e * 512 * 1024;
  for (int k0 = kbeg; k0 < kbeg + 512; k0 += 32) {
#pragma unroll
    for (int j = 0; j < 2; j++) {
      int row = 16 * (4 * j + wv) + srow;
      gload16(hid + (size_t)(m0 + row) * 1024 + k0 + skof,
              (char*)&As[0][0] + (size_t)(4 * j + wv) * 1024);
    }
#pragma unroll
    for (int j = 0; j < 2; j++) {
      int row = 16 * (4 * j + wv) + srow;
      size_t baddr = wbase + (size_t)(n0 + row) * 1024 + k0 + skof;
      if (wbf) {
        gload16((const bf16*)Wt + baddr, (char*)&Bs[0][0] + (size_t)(4 * j + wv) * 1024);
      } else {
        const float* g = (const float*)Wt + baddr;
        short8 v;
#pragma unroll
        for (int u = 0; u < 8; u++) { bf16 t = __float2bfloat16(g[u]); v[u] = *(short*)&t; }
        *(short8*)&Bs[row][skof] = v;
      }
    }
    __syncthreads();
    short8 af[4], bfr[4];
#pragma unroll
    for (int t = 0; t < 4; t++) {
      af[t]  = *(const short8*)&As[wr + t * 16 + mrow][quad * 8];
      bfr[t] = *(const short8*)&Bs[wc + t * 16 + mrow][quad * 8];
    }
#pragma unroll
    for (int i = 0; i < 4; i++)
#pragma unroll
      for (int j = 0; j < 4; j++)
        acc[i][j] = __builtin_amdgcn_mfma_f32_16x16x32_bf16(af[i], bfr[j], acc[i][j], 0, 0, 0);
    __syncthreads();
  }

#pragma unroll
  for (int ti = 0; ti < 4; ti++) {
#pragma unroll
    for (int r = 0; r < 4; r++) {
      int pos = m0 + wr + ti * 16 + quad * 4 + r;
      if (pos < en) {
        int pk = pack[pos];
        int tok = pk >> 1, rank = pk & 1;
        bf16* dst = psl + (size_t)(rank * 2 + blockIdx.z) * T_ * D_ + (size_t)tok * D_;
#pragma unroll
        for (int tj = 0; tj < 4; tj++) {
          int ncol = n0 + wc + tj * 16 + mrow;
          dst[ncol] = __float2bfloat16(acc[ti][tj][r]);
        }
      }
    }
  }
}

// ---------------- head ----------------
__global__ __launch_bounds__(256) void head_kernel(const float* __restrict__ hbuf,
                                                   const void* __restrict__ hw,
                                                   const void* __restrict__ hb,
                                                   void* __restrict__ out,
                                                   const int* __restrict__ flag) {
  const int bf = flag[0];
  int bq = blockIdx.x, tid = threadIdx.x;
  int b = bq / 3, q = bq % 3;
  __shared__ float red[256];
  const float* xr = hbuf + (size_t)(b * S_ + (S_ - 1)) * D_;
  float sacc = xr[tid] * ldin(hw, (size_t)q * D_ + tid, bf)
             + xr[tid + 256] * ldin(hw, (size_t)q * D_ + tid + 256, bf);
  red[tid] = sacc; __syncthreads();
  for (int w = 128; w; w >>= 1) { if (tid < w) red[tid] += red[tid + w]; __syncthreads(); }
  if (tid == 0) {
    float r = red[0] + ldin(hb, q, bf);
    if (bf) ((bf16*)out)[bq] = __float2bfloat16(r);
    else    ((float*)out)[bq] = r;
  }
}

extern "C" void kernel_launch(void* const* d_in, const int* in_sizes, int n_in,
                              void* d_out, int out_size, void* d_ws, size_t ws_size,
                              hipStream_t stream) {
  const void* x    = d_in[0];
  const void* Wp   = d_in[1];
  const void* bp   = d_in[2];
  const void* femb = d_in[3];
  const void* qkvw = d_in[4];
  const void* qkvb = d_in[5];
  const void* ow   = d_in[6];
  const void* ob   = d_in[7];
  const void* g1   = d_in[8];
  const void* be1  = d_in[9];
  const void* gw   = d_in[10];
  const void* gb   = d_in[11];
  const void* ew1  = d_in[12];
  const void* eb1  = d_in[13];
  const void* ew2  = d_in[14];
  const void* eb2  = d_in[15];
  const void* g2   = d_in[16];
  const void* be2  = d_in[17];
  const void* hw   = d_in[18];
  const void* hb   = d_in[19];
  const int*  freq = (const int*)d_in[20];

  // workspace layout: ~90 MB peak (proven-safe bound: 101 MB)
  int*   flag  = (int*)d_ws;                        // 64 ints
  int*   off   = flag + 64;                         // 4
  int*   endp  = off + 4;                           // 4
  int*   cur   = endp + 4;                          // 4 (+pad to 64)
  int*   einfo = flag + 128;                        // T ints
  float* w0a   = (float*)(einfo + T_);              // T
  float* w1a   = w0a + T_;                          // T
  int*   pack  = (int*)(w1a + T_);                  // CAP ints
  float* wlist = (float*)(pack + CAP_);             // CAP
  float* xn    = wlist + CAP_;                      // 65536
  float* h     = xn + 65536;                        // T*D f    (16 MB)
  float* cw    = h + (size_t)T_ * D_;               // T*4
  bf16*  hb16  = (bf16*)(cw + (size_t)T_ * E_);     // T*D bf16 (8 MB)
  bf16*  R     = hb16 + (size_t)T_ * D_;            // alias region: max(qkv+ao, hid) = 33 MB
  bf16*  qkvb16 = R;                                // T*3D bf16 (24 MB)
  bf16*  ao    = R + (size_t)T_ * D3_;              // T*D bf16  (8 MB)
  bf16*  hid   = R;                                 // CAP*1024 bf16 (~33 MB)
  bf16*  psl   = R + (size_t)CAP_ * 1024;           // 4x T*D bf16 (32 MB partial slices)

  detect_kernel<<<1, 64, 0, stream>>>(x, flag);
  instnorm_kernel<<<B_ * F_, 256, 0, stream>>>(x, xn, flag);
  input_proj_kernel<<<(T_ * D_) / 256, 256, 0, stream>>>(xn, Wp, bp, femb, freq, h, hb16, flag);

  for (int l = 0; l < 3; l++) {
    // QKV projection -> bf16
    mfma_gemm<3><<<dim3(D3_ / 128, T_ / 128), 256, 0, stream>>>(
        hb16, qkvw, (size_t)l * D3_ * D_, qkvb, (size_t)l * D3_, qkvb16,
        D_, D_, D_, D3_, flag);
    attn_kernel<<<B_ * H_ * (S_ / 128), 256, 0, stream>>>(qkvb16, ao);
    // O-projection: split-K=2 -> slices 0,1; fused reduce + bias + LN
    mfma_gemm<0><<<dim3(D_ / 128, T_ / 128, 2), 256, 0, stream>>>(
        ao, ow, (size_t)l * D_ * D_, nullptr, 0, psl,
        D_, D_, D_, D_, flag);
    reduce_ln_kernel<<<T_, 256, 0, stream>>>(
        h, hb16, psl, 2, 0, ob, (size_t)l * D_, nullptr, nullptr, 0,
        g1, be1, (size_t)l * D_, flag);
    // gating + routing
    gate_kernel<<<T_ / 4, 256, 0, stream>>>(h, gw, (size_t)l * E_ * D_, gb, (size_t)l * E_,
                                            cw, einfo, w0a, w1a, flag);
    route_scan_kernel<<<1, 256, 0, stream>>>(einfo, off, endp, cur);
    scatter_kernel<<<T_ / 256, 256, 0, stream>>>(einfo, w0a, w1a, off, cur, pack, wlist);
    // sparse expert GEMMs (hid aliases qkv+ao, both dead here)
    moe_mat1_kernel<<<dim3(8, 256), 256, 0, stream>>>(
        hb16, ew1, (size_t)l * E_ * 1024 * 512, eb1, (size_t)l * E_ * 1024, hid,
        off, endp, pack, wlist, flag);
    moe_mat2_kernel<<<dim3(4, 256, 2), 256, 0, stream>>>(
        hid, ew2, (size_t)l * E_ * 512 * 1024, psl, off, endp, pack, flag);
    reduce_ln_kernel<<<T_, 256, 0, stream>>>(
        h, hb16, psl, 4, 1, nullptr, 0, cw, eb2, (size_t)l * E_ * D_,
        g2, be2, (size_t)l * D_, flag);
  }

  head_kernel<<<24, 256, 0, stream>>>(h, hw, hb, d_out, flag);
}